// Round 1
// baseline (993.712 us; speedup 1.0000x reference)
//
#include <hip/hip_runtime.h>
#include <math.h>

#define B_ 2
#define T_ 2048
#define DM_ 1024
#define NH_ 16
#define NKV_ 4
#define G_ 4
#define DK_ 64

// ---------------------------------------------------------------- RoPE tables
__global__ __launch_bounds__(256) void rope_table_kernel(float* __restrict__ cos_t,
                                                         float* __restrict__ sin_t) {
  int idx = blockIdx.x * 256 + threadIdx.x;
  if (idx >= T_ * 32) return;
  int t = idx >> 5;
  int i = idx & 31;
  float invf = 1.0f / powf(10000.0f, (float)i / 32.0f);
  float ang = (float)t * invf;
  cos_t[idx] = cosf(ang);
  sin_t[idx] = sinf(ang);
}

// ---------------------------------------------------------------- fp32 SGEMM
// A: [4096 x 1024] row-major, W: [1024 x N] row-major.
// mode 0: out = Qr [B,NH,T,DK]; mode 1/2: out = Kr/Vr [B,NKV,T,DK]; mode 3: out[row*1024+col]
__global__ __launch_bounds__(256) void sgemm_kernel(const float* __restrict__ A,
                                                    const float* __restrict__ W,
                                                    float* __restrict__ out,
                                                    int N, int mode) {
  const int tid = threadIdx.x;
  const int ty = tid >> 4;   // 0..15 -> 4 rows each
  const int tx = tid & 15;   // 0..15 -> 4 cols each
  const int m0 = blockIdx.y * 64;
  const int n0 = blockIdx.x * 64;

  __shared__ __align__(16) float At[16 * 68];  // [k][m], pitch 68
  __shared__ __align__(16) float Bs[16 * 68];  // [k][n], pitch 68

  float acc[4][4] = {{0.f, 0.f, 0.f, 0.f}, {0.f, 0.f, 0.f, 0.f},
                     {0.f, 0.f, 0.f, 0.f}, {0.f, 0.f, 0.f, 0.f}};

  for (int kt = 0; kt < 1024 / 16; ++kt) {
    __syncthreads();
#pragma unroll
    for (int it = 0; it < 4; ++it) {
      int f = tid + 256 * it;           // 0..1023
      int m = f >> 4, kk = f & 15;
      At[kk * 68 + m] = A[(size_t)(m0 + m) * 1024 + (size_t)kt * 16 + kk];
      int n = f & 63, kb = f >> 6;
      Bs[kb * 68 + n] = W[(size_t)(kt * 16 + kb) * N + n0 + n];
    }
    __syncthreads();
#pragma unroll
    for (int kk = 0; kk < 16; ++kk) {
      float4 a4 = *(const float4*)&At[kk * 68 + ty * 4];
      float4 b4 = *(const float4*)&Bs[kk * 68 + tx * 4];
      float av[4] = {a4.x, a4.y, a4.z, a4.w};
      float bv[4] = {b4.x, b4.y, b4.z, b4.w};
#pragma unroll
      for (int i = 0; i < 4; ++i)
#pragma unroll
        for (int j = 0; j < 4; ++j) acc[i][j] += av[i] * bv[j];
    }
  }

#pragma unroll
  for (int i = 0; i < 4; ++i) {
    int row = m0 + ty * 4 + i;
    int b = row >> 11;           // T_ = 2048
    int t = row & (T_ - 1);
#pragma unroll
    for (int j = 0; j < 4; ++j) {
      int col = n0 + tx * 4 + j;
      float val = acc[i][j];
      if (mode == 0) {
        int h = col >> 6, d = col & 63;
        out[(((size_t)(b * NH_ + h)) * T_ + t) * DK_ + d] = val;
      } else if (mode == 1 || mode == 2) {
        int kvh = col >> 6, d = col & 63;
        out[(((size_t)(b * NKV_ + kvh)) * T_ + t) * DK_ + d] = val;
      } else {
        out[(size_t)row * DM_ + col] = val;
      }
    }
  }
}

// ---------------------------------------------------------------- RoPE apply (in place)
// X: nrows rows of DK_=64; out[d] = x[d]*cos - x[d+32]*sin ; out[d+32] = x[d+32]*cos + x[d]*sin
__global__ __launch_bounds__(256) void rope_apply_kernel(float* __restrict__ X,
                                                         const float* __restrict__ cos_t,
                                                         const float* __restrict__ sin_t,
                                                         int nrows) {
  int idx = blockIdx.x * 256 + threadIdx.x;
  if (idx >= nrows * 32) return;
  int row = idx >> 5;
  int d = idx & 31;
  int t = row & (T_ - 1);   // row = (b*heads + h)*T + t
  float c = cos_t[t * 32 + d];
  float s = sin_t[t * 32 + d];
  float x1 = X[(size_t)row * DK_ + d];
  float x2 = X[(size_t)row * DK_ + d + 32];
  X[(size_t)row * DK_ + d] = x1 * c - x2 * s;
  X[(size_t)row * DK_ + d + 32] = x2 * c + x1 * s;
}

// ---------------------------------------------------------------- flash attention (fp32)
// grid.x = B*NKV*G (32), grid.y = T/64 (32). Block 256 threads.
// Qr: [B,NH,T,DK], Kr/Vr: [B,NKV,T,DK]. attn_out: [B,T,NH*DK]
__global__ __launch_bounds__(256) void attn_kernel(const float* __restrict__ Qr,
                                                   const float* __restrict__ Kr,
                                                   const float* __restrict__ Vr,
                                                   float* __restrict__ attn_out) {
  const int hb = blockIdx.x;
  const int b = hb / (NKV_ * G_);
  const int kv = (hb / G_) % NKV_;
  const int g = hb % G_;
  const int h = kv * G_ + g;
  const int q0 = blockIdx.y * 64;

  const int tid = threadIdx.x;
  const int ty = tid >> 4;   // 0..15 -> q rows ty*4..ty*4+3
  const int tx = tid & 15;   // 0..15 -> key/dim cols tx*4..tx*4+3

  __shared__ __align__(16) float Qt[64 * 68];    // [d][qrow]
  __shared__ __align__(16) float KtP[64 * 68];   // [d][key] for QK^T, then P[key][qrow]
  __shared__ __align__(16) float Vs[64 * 68];    // [key][d]

  const float* Qbase = Qr + ((size_t)(b * NH_ + h) * T_ + q0) * DK_;
  const float* Kbase = Kr + (size_t)(b * NKV_ + kv) * T_ * DK_;
  const float* Vbase = Vr + (size_t)(b * NKV_ + kv) * T_ * DK_;

#pragma unroll
  for (int it = 0; it < 16; ++it) {
    int f = tid + 256 * it;        // 0..4095
    int r = f >> 6, d = f & 63;
    Qt[d * 68 + r] = Qbase[(size_t)r * DK_ + d];
  }

  float m_run[4], l_run[4], acc[4][4];
#pragma unroll
  for (int i = 0; i < 4; ++i) {
    m_run[i] = -INFINITY;
    l_run[i] = 0.f;
#pragma unroll
    for (int j = 0; j < 4; ++j) acc[i][j] = 0.f;
  }

  for (int kt = 0; kt < T_ / 64; ++kt) {
    __syncthreads();   // previous iteration's KtP/Vs reads done
#pragma unroll
    for (int it = 0; it < 16; ++it) {
      int f = tid + 256 * it;
      int r = f >> 6, d = f & 63;
      KtP[d * 68 + r] = Kbase[(size_t)(kt * 64 + r) * DK_ + d];
      Vs[r * 68 + d] = Vbase[(size_t)(kt * 64 + r) * DK_ + d];
    }
    __syncthreads();

    // scores S[4q][4k] = Q . K
    float s[4][4] = {{0.f, 0.f, 0.f, 0.f}, {0.f, 0.f, 0.f, 0.f},
                     {0.f, 0.f, 0.f, 0.f}, {0.f, 0.f, 0.f, 0.f}};
#pragma unroll 8
    for (int d = 0; d < 64; ++d) {
      float4 qa = *(const float4*)&Qt[d * 68 + ty * 4];
      float4 kb = *(const float4*)&KtP[d * 68 + tx * 4];
      float av[4] = {qa.x, qa.y, qa.z, qa.w};
      float bv[4] = {kb.x, kb.y, kb.z, kb.w};
#pragma unroll
      for (int i = 0; i < 4; ++i)
#pragma unroll
        for (int j = 0; j < 4; ++j) s[i][j] += av[i] * bv[j];
    }

    // online softmax per q row (row held by 16 lanes sharing ty)
    float alpha[4];
#pragma unroll
    for (int i = 0; i < 4; ++i) {
#pragma unroll
      for (int j = 0; j < 4; ++j) s[i][j] *= 0.125f;   // 1/sqrt(64)
      float mt = fmaxf(fmaxf(s[i][0], s[i][1]), fmaxf(s[i][2], s[i][3]));
#pragma unroll
      for (int mask = 1; mask < 16; mask <<= 1) mt = fmaxf(mt, __shfl_xor(mt, mask, 64));
      float mnew = fmaxf(m_run[i], mt);
      alpha[i] = expf(m_run[i] - mnew);   // -inf - finite -> 0 on first tile
      float rs = 0.f;
#pragma unroll
      for (int j = 0; j < 4; ++j) {
        s[i][j] = expf(s[i][j] - mnew);
        rs += s[i][j];
      }
#pragma unroll
      for (int mask = 1; mask < 16; mask <<= 1) rs += __shfl_xor(rs, mask, 64);
      l_run[i] = l_run[i] * alpha[i] + rs;
      m_run[i] = mnew;
    }

    __syncthreads();   // all KtP (K) reads complete before overwriting with P
#pragma unroll
    for (int j = 0; j < 4; ++j)
#pragma unroll
      for (int i = 0; i < 4; ++i)
        KtP[(tx * 4 + j) * 68 + ty * 4 + i] = s[i][j];   // P^T: [key][qrow]
    __syncthreads();

#pragma unroll
    for (int i = 0; i < 4; ++i)
#pragma unroll
      for (int j = 0; j < 4; ++j) acc[i][j] *= alpha[i];

#pragma unroll 8
    for (int key = 0; key < 64; ++key) {
      float4 pv = *(const float4*)&KtP[key * 68 + ty * 4];
      float4 vv = *(const float4*)&Vs[key * 68 + tx * 4];
      float pa[4] = {pv.x, pv.y, pv.z, pv.w};
      float va[4] = {vv.x, vv.y, vv.z, vv.w};
#pragma unroll
      for (int i = 0; i < 4; ++i)
#pragma unroll
        for (int j = 0; j < 4; ++j) acc[i][j] += pa[i] * va[j];
    }
  }

#pragma unroll
  for (int i = 0; i < 4; ++i) {
    float inv = 1.0f / l_run[i];
    int trow = q0 + ty * 4 + i;
#pragma unroll
    for (int j = 0; j < 4; ++j) {
      attn_out[((size_t)b * T_ + trow) * DM_ + h * DK_ + tx * 4 + j] = acc[i][j] * inv;
    }
  }
}

// ---------------------------------------------------------------- launch
extern "C" void kernel_launch(void* const* d_in, const int* in_sizes, int n_in,
                              void* d_out, int out_size, void* d_ws, size_t ws_size,
                              hipStream_t stream) {
  const float* q  = (const float*)d_in[0];
  const float* k  = (const float*)d_in[1];
  const float* v  = (const float*)d_in[2];
  const float* Wq = (const float*)d_in[3];
  const float* Wk = (const float*)d_in[4];
  const float* Wv = (const float*)d_in[5];
  const float* Wo = (const float*)d_in[6];
  float* out = (float*)d_out;

  float* ws    = (float*)d_ws;
  float* cos_t = ws;                          // T*32
  float* sin_t = cos_t + (size_t)T_ * 32;     // T*32
  float* Qr    = sin_t + (size_t)T_ * 32;     // B*NH*T*DK  = 4194304
  float* Kr    = Qr + (size_t)B_ * NH_ * T_ * DK_;   // B*NKV*T*DK = 1048576
  float* Vr    = Kr + (size_t)B_ * NKV_ * T_ * DK_;
  float* attn  = Vr + (size_t)B_ * NKV_ * T_ * DK_;  // B*T*DM = 4194304

  dim3 blk(256);

  rope_table_kernel<<<dim3(256), blk, 0, stream>>>(cos_t, sin_t);

  // projections: M=4096, K=1024
  sgemm_kernel<<<dim3(16, 64), blk, 0, stream>>>(q, Wq, Qr, 1024, 0);
  sgemm_kernel<<<dim3(4, 64), blk, 0, stream>>>(k, Wk, Kr, 256, 1);
  sgemm_kernel<<<dim3(4, 64), blk, 0, stream>>>(v, Wv, Vr, 256, 2);

  // RoPE in place on Q (B*NH*T rows) and K (B*NKV*T rows)
  {
    int nrowsQ = B_ * NH_ * T_;
    int nrowsK = B_ * NKV_ * T_;
    rope_apply_kernel<<<dim3((nrowsQ * 32) / 256), blk, 0, stream>>>(Qr, cos_t, sin_t, nrowsQ);
    rope_apply_kernel<<<dim3((nrowsK * 32) / 256), blk, 0, stream>>>(Kr, cos_t, sin_t, nrowsK);
  }

  // attention: 32 head-instances x 32 q-tiles
  attn_kernel<<<dim3(32, 32), blk, 0, stream>>>(Qr, Kr, Vr, attn);

  // output projection -> d_out
  sgemm_kernel<<<dim3(16, 64), blk, 0, stream>>>(attn, Wo, out, 1024, 3);
}

// Round 2
// 541.480 us; speedup vs baseline: 1.8352x; 1.8352x over previous
//
#include <hip/hip_runtime.h>
#include <hip/hip_bf16.h>
#include <math.h>

#define B_ 2
#define T_ 2048
#define DM_ 1024
#define NH_ 16
#define NKV_ 4
#define G_ 4
#define DK_ 64

typedef __attribute__((ext_vector_type(8))) short bf16x8;
typedef __attribute__((ext_vector_type(4))) float f32x4;
typedef __attribute__((ext_vector_type(8))) unsigned short u16x8;
typedef __attribute__((ext_vector_type(4))) unsigned short u16x4;

static __device__ __forceinline__ ushort f2bf(float x) {
  __hip_bfloat16 h = __float2bfloat16(x);
  return *reinterpret_cast<ushort*>(&h);
}

// ---------------------------------------------------------------- RoPE tables
__global__ __launch_bounds__(256) void rope_table_kernel(float* __restrict__ cos_t,
                                                         float* __restrict__ sin_t) {
  int idx = blockIdx.x * 256 + threadIdx.x;
  if (idx >= T_ * 32) return;
  int t = idx >> 5;
  int i = idx & 31;
  float invf = 1.0f / powf(10000.0f, (float)i / 32.0f);
  float ang = (float)t * invf;
  cos_t[idx] = cosf(ang);
  sin_t[idx] = sinf(ang);
}

// ---------------------------------------------------------------- fp32 SGEMM + fused epilogue
// A: [4096 x 1024] row-major f32, W: [1024 x N] row-major f32.
// mode 0: out bf16 Qb [B,NH,T,DK] with RoPE
// mode 1: out bf16 Kb [B,NKV,T,DK] with RoPE
// mode 2: out bf16 Vb [B,NKV,T,DK]
// mode 3: out f32 [row*1024+col]
__global__ __launch_bounds__(256) void sgemm_kernel(const float* __restrict__ A,
                                                    const float* __restrict__ W,
                                                    void* __restrict__ out,
                                                    int N, int mode,
                                                    const float* __restrict__ cos_t,
                                                    const float* __restrict__ sin_t) {
  const int tid = threadIdx.x;
  const int ty = tid >> 4;   // 0..15 -> 4 rows each
  const int tx = tid & 15;   // 0..15 -> 4 cols each
  const int m0 = blockIdx.y * 64;
  const int n0 = blockIdx.x * 64;

  __shared__ __align__(16) float At[16 * 68];  // [k][m], pitch 68
  __shared__ __align__(16) float Bs[16 * 68];  // [k][n], pitch 68

  float acc[4][4] = {{0.f, 0.f, 0.f, 0.f}, {0.f, 0.f, 0.f, 0.f},
                     {0.f, 0.f, 0.f, 0.f}, {0.f, 0.f, 0.f, 0.f}};

  for (int kt = 0; kt < 1024 / 16; ++kt) {
    __syncthreads();
#pragma unroll
    for (int it = 0; it < 4; ++it) {
      int f = tid + 256 * it;           // 0..1023
      int m = f >> 4, kk = f & 15;
      At[kk * 68 + m] = A[(size_t)(m0 + m) * 1024 + (size_t)kt * 16 + kk];
      int n = f & 63, kb = f >> 6;
      Bs[kb * 68 + n] = W[(size_t)(kt * 16 + kb) * N + n0 + n];
    }
    __syncthreads();
#pragma unroll
    for (int kk = 0; kk < 16; ++kk) {
      float4 a4 = *(const float4*)&At[kk * 68 + ty * 4];
      float4 b4 = *(const float4*)&Bs[kk * 68 + tx * 4];
      float av[4] = {a4.x, a4.y, a4.z, a4.w};
      float bv[4] = {b4.x, b4.y, b4.z, b4.w};
#pragma unroll
      for (int i = 0; i < 4; ++i)
#pragma unroll
        for (int j = 0; j < 4; ++j) acc[i][j] += av[i] * bv[j];
    }
  }

#pragma unroll
  for (int i = 0; i < 4; ++i) {
    int row = m0 + ty * 4 + i;
    int b = row >> 11;           // T_ = 2048
    int t = row & (T_ - 1);
    if (mode == 3) {
      float4 v = make_float4(acc[i][0], acc[i][1], acc[i][2], acc[i][3]);
      *(float4*)((float*)out + (size_t)row * DM_ + n0 + tx * 4) = v;
    } else {
      u16x4 o;
      int col0 = n0 + tx * 4;
      int h = col0 >> 6;
#pragma unroll
      for (int j = 0; j < 4; ++j) {
        int col = col0 + j;
        int d = col & 63;
        float x = acc[i][j];
        float xp = __shfl_xor(x, 8, 64);   // partner holds col ^ 32
        float val;
        if (mode == 2) {
          val = x;
        } else {
          float c = cos_t[t * 32 + (d & 31)];
          float s = sin_t[t * 32 + (d & 31)];
          val = (d < 32) ? (x * c - xp * s) : (x * c + xp * s);
        }
        o[j] = f2bf(val);
      }
      size_t base;
      if (mode == 0) base = (((size_t)(b * NH_ + h)) * T_ + t) * DK_ + (col0 & 63);
      else           base = (((size_t)(b * NKV_ + h)) * T_ + t) * DK_ + (col0 & 63);
      *(u16x4*)((ushort*)out + base) = o;
    }
  }
}

// ---------------------------------------------------------------- V transpose: Vb[bkv][t][d] -> Vt[bkv][d][t]
__global__ __launch_bounds__(256) void vtrans_kernel(const ushort* __restrict__ Vb,
                                                     ushort* __restrict__ Vt) {
  int bkv = blockIdx.x >> 5;          // T/64 = 32 t-tiles
  int t0 = (blockIdx.x & 31) << 6;
  __shared__ ushort tile[64 * 65];
  int tid = threadIdx.x;
#pragma unroll
  for (int it = 0; it < 2; ++it) {
    int c = tid + it * 256;
    int r = c >> 3, ch = c & 7;       // t-row r, d-chunk ch
    u16x8 v = *(const u16x8*)(Vb + ((size_t)bkv * T_ + t0 + r) * DK_ + ch * 8);
#pragma unroll
    for (int j = 0; j < 8; ++j) tile[(ch * 8 + j) * 65 + r] = v[j];
  }
  __syncthreads();
#pragma unroll
  for (int it = 0; it < 2; ++it) {
    int c = tid + it * 256;
    int d = c >> 3, ch = c & 7;
    u16x8 o;
#pragma unroll
    for (int j = 0; j < 8; ++j) o[j] = tile[d * 65 + ch * 8 + j];
    *(u16x8*)(Vt + ((size_t)bkv * DK_ + d) * T_ + t0 + ch * 8) = o;
  }
}

// ---------------------------------------------------------------- MFMA flash attention
// grid.x = B*NKV*G (32), grid.y = T/64 (32). 256 threads = 4 waves.
// Qb: [B,NH,T,DK] bf16, Kb: [B,NKV,T,DK] bf16, Vt: [B,NKV,DK,T] bf16.
// attn_out: [B,T,DM] f32
__global__ __launch_bounds__(256) void attn_mfma_kernel(const ushort* __restrict__ Qb,
                                                        const ushort* __restrict__ Kb,
                                                        const ushort* __restrict__ Vt,
                                                        float* __restrict__ attn_out) {
  const int hb = blockIdx.x;
  const int b = hb >> 4;            // NKV*G = 16
  const int kv = (hb >> 2) & 3;
  const int g = hb & 3;
  const int h = kv * G_ + g;
  const int q0 = blockIdx.y * 64;

  const int tid = threadIdx.x;
  const int w = tid >> 6;
  const int lane = tid & 63;
  const int lr = lane & 15;
  const int lg = lane >> 4;

  __shared__ __align__(16) ushort Qs[64 * 64];   // swizzled, pitch 128B
  __shared__ __align__(16) ushort Ks[64 * 64];
  __shared__ __align__(16) ushort Vs[64 * 64];   // [d][key]
  __shared__ __align__(16) ushort Ps[64 * 64];   // [q][key]

  const ushort* Qg = Qb + ((size_t)(b * NH_ + h) * T_ + q0) * DK_;
  const ushort* Kg = Kb + (size_t)(b * NKV_ + kv) * T_ * DK_;
  const ushort* Vg = Vt + (size_t)(b * NKV_ + kv) * DK_ * T_;

  // stage Q once (swizzled)
#pragma unroll
  for (int it = 0; it < 2; ++it) {
    int c = tid + it * 256;
    int r = c >> 3, ch = c & 7;
    u16x8 val = *(const u16x8*)(Qg + (size_t)r * DK_ + ch * 8);
    int byte = (r * 128 + ch * 16) ^ ((r & 7) << 4);
    *(u16x8*)((char*)Qs + byte) = val;
  }
  __syncthreads();

  // Q fragments (constant across KV loop)
  bf16x8 aq[2];
#pragma unroll
  for (int kc = 0; kc < 2; ++kc) {
    int qrow = w * 16 + lr;
    int byte = (qrow * 128 + kc * 64 + lg * 16) ^ ((qrow & 7) << 4);
    aq[kc] = *(bf16x8*)((char*)Qs + byte);
  }

  float m_run[4], l_run[4];
  f32x4 oacc[4];
#pragma unroll
  for (int r = 0; r < 4; ++r) {
    m_run[r] = -3.0e38f;
    l_run[r] = 0.f;
  }
#pragma unroll
  for (int dt = 0; dt < 4; ++dt) oacc[dt] = (f32x4){0.f, 0.f, 0.f, 0.f};

  u16x8 kreg[2], vreg[2];
#pragma unroll
  for (int it = 0; it < 2; ++it) {
    int c = tid + it * 256;
    int r = c >> 3, ch = c & 7;
    kreg[it] = *(const u16x8*)(Kg + (size_t)r * DK_ + ch * 8);
    vreg[it] = *(const u16x8*)(Vg + (size_t)r * T_ + ch * 8);
  }

  for (int kt = 0; kt < T_ / 64; ++kt) {
    __syncthreads();   // previous tile's reads complete
#pragma unroll
    for (int it = 0; it < 2; ++it) {
      int c = tid + it * 256;
      int r = c >> 3, ch = c & 7;
      int byte = (r * 128 + ch * 16) ^ ((r & 7) << 4);
      *(u16x8*)((char*)Ks + byte) = kreg[it];
      *(u16x8*)((char*)Vs + byte) = vreg[it];
    }
    __syncthreads();

    if (kt + 1 < T_ / 64) {   // async prefetch next tile into regs
#pragma unroll
      for (int it = 0; it < 2; ++it) {
        int c = tid + it * 256;
        int r = c >> 3, ch = c & 7;
        kreg[it] = *(const u16x8*)(Kg + (size_t)((kt + 1) * 64 + r) * DK_ + ch * 8);
        vreg[it] = *(const u16x8*)(Vg + (size_t)r * T_ + (kt + 1) * 64 + ch * 8);
      }
    }

    // ---- QK^T : S[16q x 64key] per wave
    f32x4 s[4];
#pragma unroll
    for (int nt = 0; nt < 4; ++nt) s[nt] = (f32x4){0.f, 0.f, 0.f, 0.f};
#pragma unroll
    for (int nt = 0; nt < 4; ++nt) {
#pragma unroll
      for (int kc = 0; kc < 2; ++kc) {
        int krow = nt * 16 + lr;
        int byte = (krow * 128 + kc * 64 + lg * 16) ^ ((krow & 7) << 4);
        bf16x8 bk = *(bf16x8*)((char*)Ks + byte);
        s[nt] = __builtin_amdgcn_mfma_f32_16x16x32_bf16(aq[kc], bk, s[nt], 0, 0, 0);
      }
    }

    // ---- online softmax (rows r of this lane's 16-lane group)
#pragma unroll
    for (int r = 0; r < 4; ++r) {
#pragma unroll
      for (int nt = 0; nt < 4; ++nt) s[nt][r] *= 0.125f;
      float mx = fmaxf(fmaxf(s[0][r], s[1][r]), fmaxf(s[2][r], s[3][r]));
#pragma unroll
      for (int mask = 1; mask < 16; mask <<= 1) mx = fmaxf(mx, __shfl_xor(mx, mask, 64));
      float mnew = fmaxf(m_run[r], mx);
      float alpha = __expf(m_run[r] - mnew);
      float rs = 0.f;
#pragma unroll
      for (int nt = 0; nt < 4; ++nt) {
        float p = __expf(s[nt][r] - mnew);
        s[nt][r] = p;
        rs += p;
      }
#pragma unroll
      for (int mask = 1; mask < 16; mask <<= 1) rs += __shfl_xor(rs, mask, 64);
      l_run[r] = l_run[r] * alpha + rs;
      m_run[r] = mnew;
#pragma unroll
      for (int dt = 0; dt < 4; ++dt) oacc[dt][r] *= alpha;
      // write P (bf16) to LDS, swizzled
      int prow = w * 16 + lg * 4 + r;
#pragma unroll
      for (int nt = 0; nt < 4; ++nt) {
        int key = nt * 16 + lr;
        int byte = (prow * 128 + key * 2) ^ ((prow & 7) << 4);
        *(ushort*)((char*)Ps + byte) = f2bf(s[nt][r]);
      }
    }

    // ---- PV : O[16q x 64d] accumulate (wave reads only its own 16 P rows)
#pragma unroll
    for (int kc = 0; kc < 2; ++kc) {
      int prow = w * 16 + lr;
      int pbyte = (prow * 128 + kc * 64 + lg * 16) ^ ((prow & 7) << 4);
      bf16x8 ap = *(bf16x8*)((char*)Ps + pbyte);
#pragma unroll
      for (int dt = 0; dt < 4; ++dt) {
        int vrow = dt * 16 + lr;
        int vbyte = (vrow * 128 + kc * 64 + lg * 16) ^ ((vrow & 7) << 4);
        bf16x8 bv = *(bf16x8*)((char*)Vs + vbyte);
        oacc[dt] = __builtin_amdgcn_mfma_f32_16x16x32_bf16(ap, bv, oacc[dt], 0, 0, 0);
      }
    }
  }

  // epilogue
#pragma unroll
  for (int r = 0; r < 4; ++r) {
    float inv = 1.0f / l_run[r];
    int t = q0 + w * 16 + lg * 4 + r;
#pragma unroll
    for (int dt = 0; dt < 4; ++dt) {
      int d = dt * 16 + lr;
      attn_out[((size_t)b * T_ + t) * DM_ + h * DK_ + d] = oacc[dt][r] * inv;
    }
  }
}

// ---------------------------------------------------------------- launch
extern "C" void kernel_launch(void* const* d_in, const int* in_sizes, int n_in,
                              void* d_out, int out_size, void* d_ws, size_t ws_size,
                              hipStream_t stream) {
  const float* q  = (const float*)d_in[0];
  const float* k  = (const float*)d_in[1];
  const float* v  = (const float*)d_in[2];
  const float* Wq = (const float*)d_in[3];
  const float* Wk = (const float*)d_in[4];
  const float* Wv = (const float*)d_in[5];
  const float* Wo = (const float*)d_in[6];
  float* out = (float*)d_out;

  char* ws = (char*)d_ws;
  size_t off = 0;
  float* cos_t = (float*)(ws + off); off += (size_t)T_ * 32 * 4;
  float* sin_t = (float*)(ws + off); off += (size_t)T_ * 32 * 4;
  ushort* Qb   = (ushort*)(ws + off); off += (size_t)B_ * NH_ * T_ * DK_ * 2;
  ushort* Kb   = (ushort*)(ws + off); off += (size_t)B_ * NKV_ * T_ * DK_ * 2;
  ushort* Vb   = (ushort*)(ws + off); off += (size_t)B_ * NKV_ * T_ * DK_ * 2;
  ushort* Vt   = (ushort*)(ws + off); off += (size_t)B_ * NKV_ * T_ * DK_ * 2;
  float* attn  = (float*)(ws + off);  off += (size_t)B_ * T_ * DM_ * 4;

  dim3 blk(256);

  rope_table_kernel<<<dim3(256), blk, 0, stream>>>(cos_t, sin_t);

  // projections (fp32 math, bf16+RoPE epilogue)
  sgemm_kernel<<<dim3(16, 64), blk, 0, stream>>>(q, Wq, (void*)Qb, 1024, 0, cos_t, sin_t);
  sgemm_kernel<<<dim3(4, 64), blk, 0, stream>>>(k, Wk, (void*)Kb, 256, 1, cos_t, sin_t);
  sgemm_kernel<<<dim3(4, 64), blk, 0, stream>>>(v, Wv, (void*)Vb, 256, 2, cos_t, sin_t);

  vtrans_kernel<<<dim3(B_ * NKV_ * (T_ / 64)), blk, 0, stream>>>(Vb, Vt);

  attn_mfma_kernel<<<dim3(32, 32), blk, 0, stream>>>(Qb, Kb, Vt, attn);

  // output projection -> d_out (fp32)
  sgemm_kernel<<<dim3(16, 64), blk, 0, stream>>>(attn, Wo, (void*)out, 1024, 3, cos_t, sin_t);
}

// Round 3
// 229.278 us; speedup vs baseline: 4.3341x; 2.3617x over previous
//
#include <hip/hip_runtime.h>
#include <hip/hip_bf16.h>
#include <math.h>

#define B_ 2
#define T_ 2048
#define DM_ 1024
#define NH_ 16
#define NKV_ 4
#define G_ 4
#define DK_ 64

typedef __attribute__((ext_vector_type(8))) short bf16x8;
typedef __attribute__((ext_vector_type(4))) float f32x4;
typedef __attribute__((ext_vector_type(8))) unsigned short u16x8;
typedef __attribute__((ext_vector_type(4))) unsigned short u16x4;

static __device__ __forceinline__ ushort f2bf(float x) {
  __hip_bfloat16 h = __float2bfloat16(x);
  return *reinterpret_cast<ushort*>(&h);
}

// ---------------------------------------------------------------- RoPE tables
__global__ __launch_bounds__(256) void rope_table_kernel(float* __restrict__ cos_t,
                                                         float* __restrict__ sin_t) {
  int idx = blockIdx.x * 256 + threadIdx.x;
  if (idx >= T_ * 32) return;
  int t = idx >> 5;
  int i = idx & 31;
  float invf = 1.0f / powf(10000.0f, (float)i / 32.0f);
  float ang = (float)t * invf;
  cos_t[idx] = cosf(ang);
  sin_t[idx] = sinf(ang);
}

// ---------------------------------------------------------------- f32 -> bf16 (vectorized)
__global__ __launch_bounds__(256) void f2b_kernel(const float* __restrict__ in,
                                                  ushort* __restrict__ out, int n4) {
  int i = blockIdx.x * 256 + threadIdx.x;
  if (i >= n4) return;
  float4 v = *(const float4*)(in + (size_t)i * 4);
  u16x4 o;
  o[0] = f2bf(v.x); o[1] = f2bf(v.y); o[2] = f2bf(v.z); o[3] = f2bf(v.w);
  *(u16x4*)(out + (size_t)i * 4) = o;
}

// ---------------------------------------------------------------- W [K=1024][N] f32 -> Wt [N][1024] bf16
__global__ __launch_bounds__(256) void wtrans_kernel(const float* __restrict__ W,
                                                     ushort* __restrict__ Wt, int N) {
  const int n0 = blockIdx.x * 64;
  const int k0 = blockIdx.y * 64;
  __shared__ float tile[64 * 65];
  const int tid = threadIdx.x;
#pragma unroll
  for (int it = 0; it < 4; ++it) {
    int lin = tid + it * 256;          // 0..1023
    int r = lin >> 4, c4 = lin & 15;   // k-row, n-chunk
    float4 v = *(const float4*)(W + (size_t)(k0 + r) * N + n0 + c4 * 4);
    tile[r * 65 + c4 * 4 + 0] = v.x;
    tile[r * 65 + c4 * 4 + 1] = v.y;
    tile[r * 65 + c4 * 4 + 2] = v.z;
    tile[r * 65 + c4 * 4 + 3] = v.w;
  }
  __syncthreads();
#pragma unroll
  for (int it = 0; it < 4; ++it) {
    int lin = tid + it * 256;
    int n = lin >> 4, c4 = lin & 15;   // n-row, k-chunk
    u16x4 o;
#pragma unroll
    for (int j = 0; j < 4; ++j) o[j] = f2bf(tile[(c4 * 4 + j) * 65 + n]);
    *(u16x4*)(Wt + (size_t)(n0 + n) * 1024 + k0 + c4 * 4) = o;
  }
}

// ---------------------------------------------------------------- bf16 MFMA GEMM, 128x128 tile
// A: [4096][1024] bf16 row-major. Bt: [N][1024] bf16 (pre-transposed W). C = A @ Bt^T.
// mode 0: bf16 Qb [B,NH,T,DK] + RoPE ; mode 1: bf16 Kb [B,NKV,T,DK] + RoPE
// mode 2: bf16 Vb [B,NKV,T,DK]       ; mode 3: f32 out [row][1024]
__global__ __launch_bounds__(256) void bgemm_kernel(const ushort* __restrict__ A,
                                                    const ushort* __restrict__ Bt,
                                                    void* __restrict__ out, int mode,
                                                    const float* __restrict__ cos_t,
                                                    const float* __restrict__ sin_t) {
  const int tid = threadIdx.x;
  const int w = tid >> 6, lane = tid & 63;
  const int lr = lane & 15, lg = lane >> 4;
  const int wm = w >> 1, wn = w & 1;
  const int n0 = blockIdx.x * 128;
  const int m0 = blockIdx.y * 128;

  __shared__ __align__(16) ushort As[128 * 64];   // swizzled, pitch 128B
  __shared__ __align__(16) ushort Bs[128 * 64];

  f32x4 acc[4][4];
#pragma unroll
  for (int mt = 0; mt < 4; ++mt)
#pragma unroll
    for (int nt = 0; nt < 4; ++nt) acc[mt][nt] = (f32x4){0.f, 0.f, 0.f, 0.f};

  const int sr = tid >> 3, sch = tid & 7;   // staging row (0..31 base), 16B chunk

  u16x8 areg[4], breg[4];
#pragma unroll
  for (int it = 0; it < 4; ++it) {
    int r = sr + it * 32;
    areg[it] = *(const u16x8*)(A + (size_t)(m0 + r) * 1024 + sch * 8);
    breg[it] = *(const u16x8*)(Bt + (size_t)(n0 + r) * 1024 + sch * 8);
  }

  for (int kt = 0; kt < 16; ++kt) {
    __syncthreads();
#pragma unroll
    for (int it = 0; it < 4; ++it) {
      int r = sr + it * 32;
      int byte = (r * 128 + sch * 16) ^ ((r & 7) << 4);
      *(u16x8*)((char*)As + byte) = areg[it];
      *(u16x8*)((char*)Bs + byte) = breg[it];
    }
    __syncthreads();
    if (kt + 1 < 16) {
#pragma unroll
      for (int it = 0; it < 4; ++it) {
        int r = sr + it * 32;
        areg[it] = *(const u16x8*)(A + (size_t)(m0 + r) * 1024 + (kt + 1) * 64 + sch * 8);
        breg[it] = *(const u16x8*)(Bt + (size_t)(n0 + r) * 1024 + (kt + 1) * 64 + sch * 8);
      }
    }
#pragma unroll
    for (int kc = 0; kc < 2; ++kc) {
      bf16x8 af[4], bfr[4];
#pragma unroll
      for (int mt = 0; mt < 4; ++mt) {
        int row = wm * 64 + mt * 16 + lr;
        int byte = (row * 128 + kc * 64 + lg * 16) ^ ((row & 7) << 4);
        af[mt] = *(bf16x8*)((char*)As + byte);
      }
#pragma unroll
      for (int nt = 0; nt < 4; ++nt) {
        int row = wn * 64 + nt * 16 + lr;
        int byte = (row * 128 + kc * 64 + lg * 16) ^ ((row & 7) << 4);
        bfr[nt] = *(bf16x8*)((char*)Bs + byte);
      }
#pragma unroll
      for (int mt = 0; mt < 4; ++mt)
#pragma unroll
        for (int nt = 0; nt < 4; ++nt)
          acc[mt][nt] = __builtin_amdgcn_mfma_f32_16x16x32_bf16(af[mt], bfr[nt], acc[mt][nt], 0, 0, 0);
    }
  }

  // epilogue — C/D layout: col = lane&15, row = (lane>>4)*4 + r (HW-verified)
  if (mode == 3) {
    float* O = (float*)out;
#pragma unroll
    for (int mt = 0; mt < 4; ++mt) {
      int rbase = m0 + wm * 64 + mt * 16 + lg * 4;
#pragma unroll
      for (int r = 0; r < 4; ++r)
#pragma unroll
        for (int nt = 0; nt < 4; ++nt)
          O[(size_t)(rbase + r) * DM_ + n0 + wn * 64 + nt * 16 + lr] = acc[mt][nt][r];
    }
  } else if (mode == 2) {
    ushort* O = (ushort*)out;
#pragma unroll
    for (int mt = 0; mt < 4; ++mt) {
      int rbase = m0 + wm * 64 + mt * 16 + lg * 4;
#pragma unroll
      for (int r = 0; r < 4; ++r) {
        int row = rbase + r;
        int b = row >> 11, t = row & (T_ - 1);
#pragma unroll
        for (int nt = 0; nt < 4; ++nt) {
          int col = n0 + wn * 64 + nt * 16 + lr;
          int kvh = col >> 6, d = col & 63;
          O[(((size_t)(b * NKV_ + kvh)) * T_ + t) * DK_ + d] = f2bf(acc[mt][nt][r]);
        }
      }
    }
  } else {
    ushort* O = (ushort*)out;
    const int heads = (mode == 0) ? NH_ : NKV_;
#pragma unroll
    for (int mt = 0; mt < 4; ++mt) {
      int rbase = m0 + wm * 64 + mt * 16 + lg * 4;
#pragma unroll
      for (int r = 0; r < 4; ++r) {
        int row = rbase + r;
        int b = row >> 11, t = row & (T_ - 1);
#pragma unroll
        for (int nt = 0; nt < 2; ++nt) {         // partner is nt+2 (col+32), same lane
          int col = n0 + wn * 64 + nt * 16 + lr;
          int h = col >> 6, d = nt * 16 + lr;    // d = col&63 < 32
          float c = cos_t[t * 32 + d], s = sin_t[t * 32 + d];
          float x1 = acc[mt][nt][r], x2 = acc[mt][nt + 2][r];
          size_t base = (((size_t)(b * heads + h)) * T_ + t) * DK_ + d;
          O[base] = f2bf(x1 * c - x2 * s);
          O[base + 32] = f2bf(x2 * c + x1 * s);
        }
      }
    }
  }
}

// ---------------------------------------------------------------- V transpose: Vb[bkv][t][d] -> Vt[bkv][d][t]
__global__ __launch_bounds__(256) void vtrans_kernel(const ushort* __restrict__ Vb,
                                                     ushort* __restrict__ Vt) {
  int bkv = blockIdx.x >> 5;          // T/64 = 32 t-tiles
  int t0 = (blockIdx.x & 31) << 6;
  __shared__ ushort tile[64 * 65];
  int tid = threadIdx.x;
#pragma unroll
  for (int it = 0; it < 2; ++it) {
    int c = tid + it * 256;
    int r = c >> 3, ch = c & 7;       // t-row r, d-chunk ch
    u16x8 v = *(const u16x8*)(Vb + ((size_t)bkv * T_ + t0 + r) * DK_ + ch * 8);
#pragma unroll
    for (int j = 0; j < 8; ++j) tile[(ch * 8 + j) * 65 + r] = v[j];
  }
  __syncthreads();
#pragma unroll
  for (int it = 0; it < 2; ++it) {
    int c = tid + it * 256;
    int d = c >> 3, ch = c & 7;
    u16x8 o;
#pragma unroll
    for (int j = 0; j < 8; ++j) o[j] = tile[d * 65 + ch * 8 + j];
    *(u16x8*)(Vt + ((size_t)bkv * DK_ + d) * T_ + t0 + ch * 8) = o;
  }
}

// ---------------------------------------------------------------- MFMA flash attention
// grid.x = B*NKV*G (32), grid.y = T/64 (32). 256 threads = 4 waves.
// Qb: [B,NH,T,DK] bf16, Kb: [B,NKV,T,DK] bf16, Vt: [B,NKV,DK,T] bf16.
// attn_out: [B,T,DM] bf16
__global__ __launch_bounds__(256) void attn_mfma_kernel(const ushort* __restrict__ Qb,
                                                        const ushort* __restrict__ Kb,
                                                        const ushort* __restrict__ Vt,
                                                        ushort* __restrict__ attn_out) {
  const int hb = blockIdx.x;
  const int b = hb >> 4;            // NKV*G = 16
  const int kv = (hb >> 2) & 3;
  const int g = hb & 3;
  const int h = kv * G_ + g;
  const int q0 = blockIdx.y * 64;

  const int tid = threadIdx.x;
  const int w = tid >> 6;
  const int lane = tid & 63;
  const int lr = lane & 15;
  const int lg = lane >> 4;

  __shared__ __align__(16) ushort Qs[64 * 64];   // swizzled, pitch 128B
  __shared__ __align__(16) ushort Ks[64 * 64];
  __shared__ __align__(16) ushort Vs[64 * 64];   // [d][key]
  __shared__ __align__(16) ushort Ps[64 * 64];   // [q][key]

  const ushort* Qg = Qb + ((size_t)(b * NH_ + h) * T_ + q0) * DK_;
  const ushort* Kg = Kb + (size_t)(b * NKV_ + kv) * T_ * DK_;
  const ushort* Vg = Vt + (size_t)(b * NKV_ + kv) * DK_ * T_;

  // stage Q once (swizzled)
#pragma unroll
  for (int it = 0; it < 2; ++it) {
    int c = tid + it * 256;
    int r = c >> 3, ch = c & 7;
    u16x8 val = *(const u16x8*)(Qg + (size_t)r * DK_ + ch * 8);
    int byte = (r * 128 + ch * 16) ^ ((r & 7) << 4);
    *(u16x8*)((char*)Qs + byte) = val;
  }
  __syncthreads();

  // Q fragments (constant across KV loop)
  bf16x8 aq[2];
#pragma unroll
  for (int kc = 0; kc < 2; ++kc) {
    int qrow = w * 16 + lr;
    int byte = (qrow * 128 + kc * 64 + lg * 16) ^ ((qrow & 7) << 4);
    aq[kc] = *(bf16x8*)((char*)Qs + byte);
  }

  float m_run[4], l_run[4];
  f32x4 oacc[4];
#pragma unroll
  for (int r = 0; r < 4; ++r) {
    m_run[r] = -3.0e38f;
    l_run[r] = 0.f;
  }
#pragma unroll
  for (int dt = 0; dt < 4; ++dt) oacc[dt] = (f32x4){0.f, 0.f, 0.f, 0.f};

  u16x8 kreg[2], vreg[2];
#pragma unroll
  for (int it = 0; it < 2; ++it) {
    int c = tid + it * 256;
    int r = c >> 3, ch = c & 7;
    kreg[it] = *(const u16x8*)(Kg + (size_t)r * DK_ + ch * 8);
    vreg[it] = *(const u16x8*)(Vg + (size_t)r * T_ + ch * 8);
  }

  for (int kt = 0; kt < T_ / 64; ++kt) {
    __syncthreads();   // previous tile's reads complete
#pragma unroll
    for (int it = 0; it < 2; ++it) {
      int c = tid + it * 256;
      int r = c >> 3, ch = c & 7;
      int byte = (r * 128 + ch * 16) ^ ((r & 7) << 4);
      *(u16x8*)((char*)Ks + byte) = kreg[it];
      *(u16x8*)((char*)Vs + byte) = vreg[it];
    }
    __syncthreads();

    if (kt + 1 < T_ / 64) {   // prefetch next tile into regs
#pragma unroll
      for (int it = 0; it < 2; ++it) {
        int c = tid + it * 256;
        int r = c >> 3, ch = c & 7;
        kreg[it] = *(const u16x8*)(Kg + (size_t)((kt + 1) * 64 + r) * DK_ + ch * 8);
        vreg[it] = *(const u16x8*)(Vg + (size_t)r * T_ + (kt + 1) * 64 + ch * 8);
      }
    }

    // ---- QK^T : S[16q x 64key] per wave
    f32x4 s[4];
#pragma unroll
    for (int nt = 0; nt < 4; ++nt) s[nt] = (f32x4){0.f, 0.f, 0.f, 0.f};
#pragma unroll
    for (int nt = 0; nt < 4; ++nt) {
#pragma unroll
      for (int kc = 0; kc < 2; ++kc) {
        int krow = nt * 16 + lr;
        int byte = (krow * 128 + kc * 64 + lg * 16) ^ ((krow & 7) << 4);
        bf16x8 bk = *(bf16x8*)((char*)Ks + byte);
        s[nt] = __builtin_amdgcn_mfma_f32_16x16x32_bf16(aq[kc], bk, s[nt], 0, 0, 0);
      }
    }

    // ---- online softmax (rows r of this lane's 16-lane group)
#pragma unroll
    for (int r = 0; r < 4; ++r) {
#pragma unroll
      for (int nt = 0; nt < 4; ++nt) s[nt][r] *= 0.125f;
      float mx = fmaxf(fmaxf(s[0][r], s[1][r]), fmaxf(s[2][r], s[3][r]));
#pragma unroll
      for (int mask = 1; mask < 16; mask <<= 1) mx = fmaxf(mx, __shfl_xor(mx, mask, 64));
      float mnew = fmaxf(m_run[r], mx);
      float alpha = __expf(m_run[r] - mnew);
      float rs = 0.f;
#pragma unroll
      for (int nt = 0; nt < 4; ++nt) {
        float p = __expf(s[nt][r] - mnew);
        s[nt][r] = p;
        rs += p;
      }
#pragma unroll
      for (int mask = 1; mask < 16; mask <<= 1) rs += __shfl_xor(rs, mask, 64);
      l_run[r] = l_run[r] * alpha + rs;
      m_run[r] = mnew;
#pragma unroll
      for (int dt = 0; dt < 4; ++dt) oacc[dt][r] *= alpha;
      // write P (bf16) to LDS, swizzled
      int prow = w * 16 + lg * 4 + r;
#pragma unroll
      for (int nt = 0; nt < 4; ++nt) {
        int key = nt * 16 + lr;
        int byte = (prow * 128 + key * 2) ^ ((prow & 7) << 4);
        *(ushort*)((char*)Ps + byte) = f2bf(s[nt][r]);
      }
    }

    // ---- PV : O[16q x 64d] accumulate
#pragma unroll
    for (int kc = 0; kc < 2; ++kc) {
      int prow = w * 16 + lr;
      int pbyte = (prow * 128 + kc * 64 + lg * 16) ^ ((prow & 7) << 4);
      bf16x8 ap = *(bf16x8*)((char*)Ps + pbyte);
#pragma unroll
      for (int dt = 0; dt < 4; ++dt) {
        int vrow = dt * 16 + lr;
        int vbyte = (vrow * 128 + kc * 64 + lg * 16) ^ ((vrow & 7) << 4);
        bf16x8 bv = *(bf16x8*)((char*)Vs + vbyte);
        oacc[dt] = __builtin_amdgcn_mfma_f32_16x16x32_bf16(ap, bv, oacc[dt], 0, 0, 0);
      }
    }
  }

  // epilogue -> bf16
#pragma unroll
  for (int r = 0; r < 4; ++r) {
    float inv = 1.0f / l_run[r];
    int t = q0 + w * 16 + lg * 4 + r;
#pragma unroll
    for (int dt = 0; dt < 4; ++dt) {
      int d = dt * 16 + lr;
      attn_out[((size_t)b * T_ + t) * DM_ + h * DK_ + d] = f2bf(oacc[dt][r] * inv);
    }
  }
}

// ---------------------------------------------------------------- launch
extern "C" void kernel_launch(void* const* d_in, const int* in_sizes, int n_in,
                              void* d_out, int out_size, void* d_ws, size_t ws_size,
                              hipStream_t stream) {
  const float* q  = (const float*)d_in[0];
  const float* k  = (const float*)d_in[1];
  const float* v  = (const float*)d_in[2];
  const float* Wq = (const float*)d_in[3];
  const float* Wk = (const float*)d_in[4];
  const float* Wv = (const float*)d_in[5];
  const float* Wo = (const float*)d_in[6];
  float* out = (float*)d_out;

  char* ws = (char*)d_ws;
  size_t off = 0;
  float* cos_t = (float*)(ws + off); off += (size_t)T_ * 32 * 4;
  float* sin_t = (float*)(ws + off); off += (size_t)T_ * 32 * 4;
  ushort* Ab   = (ushort*)(ws + off); off += (size_t)4096 * 1024 * 2;   // activations bf16 / attnb
  ushort* Wqt  = (ushort*)(ws + off); off += (size_t)1024 * 1024 * 2;
  ushort* Wkt  = (ushort*)(ws + off); off += (size_t)256 * 1024 * 2;
  ushort* Wvt  = (ushort*)(ws + off); off += (size_t)256 * 1024 * 2;
  ushort* Wot  = (ushort*)(ws + off); off += (size_t)1024 * 1024 * 2;
  ushort* Qb   = (ushort*)(ws + off); off += (size_t)B_ * NH_ * T_ * DK_ * 2;
  ushort* Kb   = (ushort*)(ws + off); off += (size_t)B_ * NKV_ * T_ * DK_ * 2;
  ushort* Vb   = (ushort*)(ws + off); off += (size_t)B_ * NKV_ * T_ * DK_ * 2;
  ushort* Vt   = (ushort*)(ws + off); off += (size_t)B_ * NKV_ * T_ * DK_ * 2;

  dim3 blk(256);
  const int n4 = 4096 * 1024 / 4;

  rope_table_kernel<<<dim3(256), blk, 0, stream>>>(cos_t, sin_t);

  // weights -> bf16 transposed
  wtrans_kernel<<<dim3(16, 16), blk, 0, stream>>>(Wq, Wqt, 1024);
  wtrans_kernel<<<dim3(4, 16), blk, 0, stream>>>(Wk, Wkt, 256);
  wtrans_kernel<<<dim3(4, 16), blk, 0, stream>>>(Wv, Wvt, 256);
  wtrans_kernel<<<dim3(16, 16), blk, 0, stream>>>(Wo, Wot, 1024);

  // Q projection (+RoPE)
  f2b_kernel<<<dim3(n4 / 256), blk, 0, stream>>>(q, Ab, n4);
  bgemm_kernel<<<dim3(8, 32), blk, 0, stream>>>(Ab, Wqt, (void*)Qb, 0, cos_t, sin_t);
  // K projection (+RoPE)
  f2b_kernel<<<dim3(n4 / 256), blk, 0, stream>>>(k, Ab, n4);
  bgemm_kernel<<<dim3(2, 32), blk, 0, stream>>>(Ab, Wkt, (void*)Kb, 1, cos_t, sin_t);
  // V projection
  f2b_kernel<<<dim3(n4 / 256), blk, 0, stream>>>(v, Ab, n4);
  bgemm_kernel<<<dim3(2, 32), blk, 0, stream>>>(Ab, Wvt, (void*)Vb, 2, cos_t, sin_t);

  vtrans_kernel<<<dim3(B_ * NKV_ * (T_ / 64)), blk, 0, stream>>>(Vb, Vt);

  // attention -> bf16 into Ab (dead after V projection)
  attn_mfma_kernel<<<dim3(32, 32), blk, 0, stream>>>(Qb, Kb, Vt, Ab);

  // output projection -> d_out (f32)
  bgemm_kernel<<<dim3(8, 32), blk, 0, stream>>>(Ab, Wot, (void*)out, 3, cos_t, sin_t);
}

// Round 4
// 148.210 us; speedup vs baseline: 6.7047x; 1.5470x over previous
//
#include <hip/hip_runtime.h>
#include <hip/hip_bf16.h>
#include <math.h>

#define B_ 2
#define T_ 2048
#define DM_ 1024
#define NH_ 16
#define NKV_ 4
#define G_ 4
#define DK_ 64
#define SCL 0.1803368784f   // 0.125 * log2(e) — folded into Q projection

typedef __attribute__((ext_vector_type(8))) short bf16x8;
typedef __attribute__((ext_vector_type(4))) float f32x4;
typedef __attribute__((ext_vector_type(8))) unsigned short u16x8;
typedef __attribute__((ext_vector_type(4))) unsigned short u16x4;

static __device__ __forceinline__ ushort f2bf(float x) {
  __hip_bfloat16 h = __float2bfloat16(x);
  return *reinterpret_cast<ushort*>(&h);
}

// ---------------------------------------------------------------- RoPE tables
__global__ __launch_bounds__(256) void rope_table_kernel(float* __restrict__ cos_t,
                                                         float* __restrict__ sin_t) {
  int idx = blockIdx.x * 256 + threadIdx.x;
  if (idx >= T_ * 32) return;
  int t = idx >> 5;
  int i = idx & 31;
  float invf = 1.0f / powf(10000.0f, (float)i / 32.0f);
  float ang = (float)t * invf;
  cos_t[idx] = cosf(ang);
  sin_t[idx] = sinf(ang);
}

// ---------------------------------------------------------------- W [K=1024][N] f32 -> Wt [N][1024] bf16
__global__ __launch_bounds__(256) void wtrans_kernel(const float* __restrict__ W,
                                                     ushort* __restrict__ Wt, int N) {
  const int n0 = blockIdx.x * 64;
  const int k0 = blockIdx.y * 64;
  __shared__ float tile[64 * 65];
  const int tid = threadIdx.x;
#pragma unroll
  for (int it = 0; it < 4; ++it) {
    int lin = tid + it * 256;
    int r = lin >> 4, c4 = lin & 15;
    float4 v = *(const float4*)(W + (size_t)(k0 + r) * N + n0 + c4 * 4);
    tile[r * 65 + c4 * 4 + 0] = v.x;
    tile[r * 65 + c4 * 4 + 1] = v.y;
    tile[r * 65 + c4 * 4 + 2] = v.z;
    tile[r * 65 + c4 * 4 + 3] = v.w;
  }
  __syncthreads();
#pragma unroll
  for (int it = 0; it < 4; ++it) {
    int lin = tid + it * 256;
    int n = lin >> 4, c4 = lin & 15;
    u16x4 o;
#pragma unroll
    for (int j = 0; j < 4; ++j) o[j] = f2bf(tile[(c4 * 4 + j) * 65 + n]);
    *(u16x4*)(Wt + (size_t)(n0 + n) * 1024 + k0 + c4 * 4) = o;
  }
}

// ---------------------------------------------------------------- bf16 MFMA GEMM, 64x128 tile
// A: [4096][1024] f32 (aF32=1) or bf16 (aF32=0). Bt: [N][1024] bf16. C = A @ Bt^T.
// mode 0: Qb bf16 + RoPE*SCL | mode 4: K-half -> out(+RoPE), V-half -> out + KVOFF (A=Ain2)
// mode 3: f32 out [row][1024]
#define KVOFF ((size_t)B_ * NKV_ * T_ * DK_)
__global__ __launch_bounds__(256) void bgemm_kernel(const void* __restrict__ Ain, int aF32,
                                                    const void* __restrict__ Ain2,
                                                    const ushort* __restrict__ Bt,
                                                    void* __restrict__ out, int mode,
                                                    const float* __restrict__ cos_t,
                                                    const float* __restrict__ sin_t) {
  const int tid = threadIdx.x;
  const int w = tid >> 6, lane = tid & 63;
  const int lr = lane & 15, lg = lane >> 4;
  const int wm = w >> 1, wn = w & 1;
  const int n0 = blockIdx.x * 128;
  const int m0 = blockIdx.y * 64;

  int emode = mode;
  int nbase = n0;
  const void* Asel = Ain;
  if (mode == 4) {
    if (n0 < 256) { emode = 1; } else { emode = 2; nbase = n0 - 256; Asel = Ain2; }
  }

  __shared__ __align__(16) ushort As[64 * 64];    // pitch 128B, swizzled
  __shared__ __align__(16) ushort Bs[128 * 64];

  f32x4 acc[2][4];
#pragma unroll
  for (int mt = 0; mt < 2; ++mt)
#pragma unroll
    for (int nt = 0; nt < 4; ++nt) acc[mt][nt] = (f32x4){0.f, 0.f, 0.f, 0.f};

  const int sr = tid >> 3, sch = tid & 7;

  float4 apf[2][2];
  u16x8 apb[2];
  u16x8 bpf[4];
  if (aF32) {
    const float* Af = (const float*)Asel;
#pragma unroll
    for (int it = 0; it < 2; ++it) {
      int r = sr + it * 32;
      apf[it][0] = *(const float4*)(Af + (size_t)(m0 + r) * 1024 + sch * 8);
      apf[it][1] = *(const float4*)(Af + (size_t)(m0 + r) * 1024 + sch * 8 + 4);
    }
  } else {
    const ushort* Au = (const ushort*)Asel;
#pragma unroll
    for (int it = 0; it < 2; ++it) {
      int r = sr + it * 32;
      apb[it] = *(const u16x8*)(Au + (size_t)(m0 + r) * 1024 + sch * 8);
    }
  }
#pragma unroll
  for (int it = 0; it < 4; ++it) {
    int r = sr + it * 32;
    bpf[it] = *(const u16x8*)(Bt + (size_t)(n0 + r) * 1024 + sch * 8);
  }

  for (int kt = 0; kt < 16; ++kt) {
    __syncthreads();
#pragma unroll
    for (int it = 0; it < 2; ++it) {
      int r = sr + it * 32;
      int byte = (r * 128 + sch * 16) ^ ((r & 7) << 4);
      u16x8 aw;
      if (aF32) {
        aw[0] = f2bf(apf[it][0].x); aw[1] = f2bf(apf[it][0].y);
        aw[2] = f2bf(apf[it][0].z); aw[3] = f2bf(apf[it][0].w);
        aw[4] = f2bf(apf[it][1].x); aw[5] = f2bf(apf[it][1].y);
        aw[6] = f2bf(apf[it][1].z); aw[7] = f2bf(apf[it][1].w);
      } else {
        aw = apb[it];
      }
      *(u16x8*)((char*)As + byte) = aw;
    }
#pragma unroll
    for (int it = 0; it < 4; ++it) {
      int r = sr + it * 32;
      int byte = (r * 128 + sch * 16) ^ ((r & 7) << 4);
      *(u16x8*)((char*)Bs + byte) = bpf[it];
    }
    __syncthreads();

    if (kt + 1 < 16) {
      if (aF32) {
        const float* Af = (const float*)Asel;
#pragma unroll
        for (int it = 0; it < 2; ++it) {
          int r = sr + it * 32;
          apf[it][0] = *(const float4*)(Af + (size_t)(m0 + r) * 1024 + (kt + 1) * 64 + sch * 8);
          apf[it][1] = *(const float4*)(Af + (size_t)(m0 + r) * 1024 + (kt + 1) * 64 + sch * 8 + 4);
        }
      } else {
        const ushort* Au = (const ushort*)Asel;
#pragma unroll
        for (int it = 0; it < 2; ++it) {
          int r = sr + it * 32;
          apb[it] = *(const u16x8*)(Au + (size_t)(m0 + r) * 1024 + (kt + 1) * 64 + sch * 8);
        }
      }
#pragma unroll
      for (int it = 0; it < 4; ++it) {
        int r = sr + it * 32;
        bpf[it] = *(const u16x8*)(Bt + (size_t)(n0 + r) * 1024 + (kt + 1) * 64 + sch * 8);
      }
    }

    __builtin_amdgcn_s_setprio(1);
#pragma unroll
    for (int kc = 0; kc < 2; ++kc) {
      bf16x8 af[2], bfr[4];
#pragma unroll
      for (int mt = 0; mt < 2; ++mt) {
        int row = wm * 32 + mt * 16 + lr;
        int byte = (row * 128 + kc * 64 + lg * 16) ^ ((row & 7) << 4);
        af[mt] = *(bf16x8*)((char*)As + byte);
      }
#pragma unroll
      for (int nt = 0; nt < 4; ++nt) {
        int row = wn * 64 + nt * 16 + lr;
        int byte = (row * 128 + kc * 64 + lg * 16) ^ ((row & 7) << 4);
        bfr[nt] = *(bf16x8*)((char*)Bs + byte);
      }
#pragma unroll
      for (int mt = 0; mt < 2; ++mt)
#pragma unroll
        for (int nt = 0; nt < 4; ++nt)
          acc[mt][nt] = __builtin_amdgcn_mfma_f32_16x16x32_bf16(af[mt], bfr[nt], acc[mt][nt], 0, 0, 0);
    }
    __builtin_amdgcn_s_setprio(0);
  }

  // epilogue — C/D layout: col = lane&15, row = (lane>>4)*4 + r
  if (emode == 3) {
    float* O = (float*)out;
#pragma unroll
    for (int mt = 0; mt < 2; ++mt) {
      int rbase = m0 + wm * 32 + mt * 16 + lg * 4;
#pragma unroll
      for (int r = 0; r < 4; ++r)
#pragma unroll
        for (int nt = 0; nt < 4; ++nt)
          O[(size_t)(rbase + r) * DM_ + n0 + wn * 64 + nt * 16 + lr] = acc[mt][nt][r];
    }
  } else if (emode == 2) {
    ushort* O = (ushort*)out + KVOFF;   // V buffer follows K buffer
#pragma unroll
    for (int mt = 0; mt < 2; ++mt) {
      int rbase = m0 + wm * 32 + mt * 16 + lg * 4;
#pragma unroll
      for (int r = 0; r < 4; ++r) {
        int row = rbase + r;
        int b = row >> 11, t = row & (T_ - 1);
#pragma unroll
        for (int nt = 0; nt < 4; ++nt) {
          int col = nbase + wn * 64 + nt * 16 + lr;
          int kvh = col >> 6, d = col & 63;
          O[(((size_t)(b * NKV_ + kvh)) * T_ + t) * DK_ + d] = f2bf(acc[mt][nt][r]);
        }
      }
    }
  } else {  // emode 0 (Q, *SCL) or 1 (K): RoPE
    ushort* O = (ushort*)out;
    const int heads = (emode == 0) ? NH_ : NKV_;
    const float scl = (emode == 0) ? SCL : 1.0f;
#pragma unroll
    for (int mt = 0; mt < 2; ++mt) {
      int rbase = m0 + wm * 32 + mt * 16 + lg * 4;
#pragma unroll
      for (int r = 0; r < 4; ++r) {
        int row = rbase + r;
        int b = row >> 11, t = row & (T_ - 1);
#pragma unroll
        for (int nt = 0; nt < 2; ++nt) {          // partner is nt+2 (d+32), same lane
          int col = nbase + wn * 64 + nt * 16 + lr;
          int h = col >> 6, d = nt * 16 + lr;     // d = col&63 < 32
          float c = cos_t[t * 32 + d], s = sin_t[t * 32 + d];
          float x1 = acc[mt][nt][r], x2 = acc[mt][nt + 2][r];
          size_t base = (((size_t)(b * heads + h)) * T_ + t) * DK_ + d;
          O[base] = f2bf((x1 * c - x2 * s) * scl);
          O[base + 32] = f2bf((x2 * c + x1 * s) * scl);
        }
      }
    }
  }
}

// ---------------------------------------------------------------- V transpose: Vb[bkv][t][d] -> Vt[bkv][d][t]
__global__ __launch_bounds__(256) void vtrans_kernel(const ushort* __restrict__ Vb,
                                                     ushort* __restrict__ Vt) {
  int bkv = blockIdx.x >> 5;
  int t0 = (blockIdx.x & 31) << 6;
  __shared__ ushort tile[64 * 65];
  int tid = threadIdx.x;
#pragma unroll
  for (int it = 0; it < 2; ++it) {
    int c = tid + it * 256;
    int r = c >> 3, ch = c & 7;
    u16x8 v = *(const u16x8*)(Vb + ((size_t)bkv * T_ + t0 + r) * DK_ + ch * 8);
#pragma unroll
    for (int j = 0; j < 8; ++j) tile[(ch * 8 + j) * 65 + r] = v[j];
  }
  __syncthreads();
#pragma unroll
  for (int it = 0; it < 2; ++it) {
    int c = tid + it * 256;
    int d = c >> 3, ch = c & 7;
    u16x8 o;
#pragma unroll
    for (int j = 0; j < 8; ++j) o[j] = tile[d * 65 + ch * 8 + j];
    *(u16x8*)(Vt + ((size_t)bkv * DK_ + d) * T_ + t0 + ch * 8) = o;
  }
}

// ---------------------------------------------------------------- MFMA flash attention v2
// Swapped QK^T (S^T = K·Q^T -> lane-local softmax), QBLK=128, exp2 domain.
// grid.x = B*NKV*G (32), grid.y = T/128 (16). 256 threads = 4 waves.
__global__ __launch_bounds__(256) void attn_mfma_kernel(const ushort* __restrict__ Qb,
                                                        const ushort* __restrict__ Kb,
                                                        const ushort* __restrict__ Vt,
                                                        ushort* __restrict__ attn_out) {
  const int hb = blockIdx.x;
  const int b = hb >> 4;
  const int kv = (hb >> 2) & 3;
  const int g = hb & 3;
  const int h = kv * G_ + g;
  const int q0 = blockIdx.y * 128;

  const int tid = threadIdx.x;
  const int w = tid >> 6;
  const int lane = tid & 63;
  const int lr = lane & 15;
  const int lg = lane >> 4;

  __shared__ __align__(16) ushort Qs[128 * 64];
  __shared__ __align__(16) ushort Ks[64 * 64];
  __shared__ __align__(16) ushort Vs[64 * 64];   // [d][key]
  __shared__ __align__(16) ushort Ps[128 * 64];  // [q][key]

  const ushort* Qg = Qb + ((size_t)(b * NH_ + h) * T_ + q0) * DK_;
  const ushort* Kg = Kb + (size_t)(b * NKV_ + kv) * T_ * DK_;
  const ushort* Vg = Vt + (size_t)(b * NKV_ + kv) * DK_ * T_;

  const int sr = tid >> 3, sch = tid & 7;

#pragma unroll
  for (int it = 0; it < 4; ++it) {
    int r = sr + it * 32;
    u16x8 val = *(const u16x8*)(Qg + (size_t)r * DK_ + sch * 8);
    int byte = (r * 128 + sch * 16) ^ ((r & 7) << 4);
    *(u16x8*)((char*)Qs + byte) = val;
  }
  __syncthreads();

  bf16x8 aq[2][2];
#pragma unroll
  for (int qs = 0; qs < 2; ++qs)
#pragma unroll
    for (int kc = 0; kc < 2; ++kc) {
      int qrow = qs * 64 + w * 16 + lr;
      int byte = (qrow * 128 + kc * 64 + lg * 16) ^ ((qrow & 7) << 4);
      aq[qs][kc] = *(bf16x8*)((char*)Qs + byte);
    }

  float m_run[2] = {-3.0e38f, -3.0e38f};
  float l_run[2] = {0.f, 0.f};
  f32x4 oacc[2][4];
#pragma unroll
  for (int qs = 0; qs < 2; ++qs)
#pragma unroll
    for (int dt = 0; dt < 4; ++dt) oacc[qs][dt] = (f32x4){0.f, 0.f, 0.f, 0.f};

  u16x8 kreg[2], vreg[2];
#pragma unroll
  for (int it = 0; it < 2; ++it) {
    int r = sr + it * 32;
    kreg[it] = *(const u16x8*)(Kg + (size_t)r * DK_ + sch * 8);
    vreg[it] = *(const u16x8*)(Vg + (size_t)r * T_ + sch * 8);
  }

  for (int kt = 0; kt < T_ / 64; ++kt) {
    __syncthreads();
#pragma unroll
    for (int it = 0; it < 2; ++it) {
      int r = sr + it * 32;
      int byte = (r * 128 + sch * 16) ^ ((r & 7) << 4);
      *(u16x8*)((char*)Ks + byte) = kreg[it];
      *(u16x8*)((char*)Vs + byte) = vreg[it];
    }
    __syncthreads();

    if (kt + 1 < T_ / 64) {
#pragma unroll
      for (int it = 0; it < 2; ++it) {
        int r = sr + it * 32;
        kreg[it] = *(const u16x8*)(Kg + (size_t)((kt + 1) * 64 + r) * DK_ + sch * 8);
        vreg[it] = *(const u16x8*)(Vg + (size_t)r * T_ + (kt + 1) * 64 + sch * 8);
      }
    }

    f32x4 st[2][4];
#pragma unroll
    for (int qs = 0; qs < 2; ++qs)
#pragma unroll
      for (int nt = 0; nt < 4; ++nt) st[qs][nt] = (f32x4){0.f, 0.f, 0.f, 0.f};

    __builtin_amdgcn_s_setprio(1);
#pragma unroll
    for (int kc = 0; kc < 2; ++kc) {
      bf16x8 bk[4];
#pragma unroll
      for (int nt = 0; nt < 4; ++nt) {
        int krow = nt * 16 + lr;
        int byte = (krow * 128 + kc * 64 + lg * 16) ^ ((krow & 7) << 4);
        bk[nt] = *(bf16x8*)((char*)Ks + byte);
      }
#pragma unroll
      for (int qs = 0; qs < 2; ++qs)
#pragma unroll
        for (int nt = 0; nt < 4; ++nt)
          st[qs][nt] = __builtin_amdgcn_mfma_f32_16x16x32_bf16(bk[nt], aq[qs][kc], st[qs][nt], 0, 0, 0);
    }
    __builtin_amdgcn_s_setprio(0);

    float mx[2];
#pragma unroll
    for (int qs = 0; qs < 2; ++qs) {
      float m = st[qs][0][0];
#pragma unroll
      for (int nt = 0; nt < 4; ++nt)
#pragma unroll
        for (int r = 0; r < 4; ++r) m = fmaxf(m, st[qs][nt][r]);
      m = fmaxf(m, __shfl_xor(m, 16, 64));
      m = fmaxf(m, __shfl_xor(m, 32, 64));
      mx[qs] = m;
    }
    bool need = (mx[0] > m_run[0] + 10.f) || (mx[1] > m_run[1] + 10.f);
    if (__any(need)) {
#pragma unroll
      for (int qs = 0; qs < 2; ++qs) {
        float mnew = fmaxf(m_run[qs], mx[qs]);
        float alpha = exp2f(m_run[qs] - mnew);
        l_run[qs] *= alpha;
        m_run[qs] = mnew;
#pragma unroll
        for (int dt = 0; dt < 4; ++dt) oacc[qs][dt] *= alpha;
      }
    }
#pragma unroll
    for (int qs = 0; qs < 2; ++qs) {
      int prow = qs * 64 + w * 16 + lr;
      float rs = 0.f;
#pragma unroll
      for (int nt = 0; nt < 4; ++nt) {
        u16x4 pk;
#pragma unroll
        for (int r = 0; r < 4; ++r) {
          float p = exp2f(st[qs][nt][r] - m_run[qs]);
          rs += p;
          pk[r] = f2bf(p);
        }
        int byte = (prow * 128 + (nt * 16 + lg * 4) * 2) ^ ((prow & 7) << 4);
        *(u16x4*)((char*)Ps + byte) = pk;
      }
      rs += __shfl_xor(rs, 16, 64);
      rs += __shfl_xor(rs, 32, 64);
      l_run[qs] += rs;
    }

    __builtin_amdgcn_s_setprio(1);
#pragma unroll
    for (int kc = 0; kc < 2; ++kc) {
      bf16x8 ap[2], bv[4];
#pragma unroll
      for (int qs = 0; qs < 2; ++qs) {
        int prow = qs * 64 + w * 16 + lr;
        int byte = (prow * 128 + kc * 64 + lg * 16) ^ ((prow & 7) << 4);
        ap[qs] = *(bf16x8*)((char*)Ps + byte);
      }
#pragma unroll
      for (int dt = 0; dt < 4; ++dt) {
        int vrow = dt * 16 + lr;
        int byte = (vrow * 128 + kc * 64 + lg * 16) ^ ((vrow & 7) << 4);
        bv[dt] = *(bf16x8*)((char*)Vs + byte);
      }
#pragma unroll
      for (int qs = 0; qs < 2; ++qs)
#pragma unroll
        for (int dt = 0; dt < 4; ++dt)
          oacc[qs][dt] = __builtin_amdgcn_mfma_f32_16x16x32_bf16(ap[qs], bv[dt], oacc[qs][dt], 0, 0, 0);
    }
    __builtin_amdgcn_s_setprio(0);
  }

#pragma unroll
  for (int qs = 0; qs < 2; ++qs)
#pragma unroll
    for (int r = 0; r < 4; ++r) {
      float li = __shfl(l_run[qs], (lane & 48) | (lg * 4 + r), 64);
      float inv = 1.0f / li;
      int t = q0 + qs * 64 + w * 16 + lg * 4 + r;
#pragma unroll
      for (int dt = 0; dt < 4; ++dt) {
        int d = dt * 16 + lr;
        attn_out[((size_t)b * T_ + t) * DM_ + h * DK_ + d] = f2bf(oacc[qs][dt][r] * inv);
      }
    }
}

// ---------------------------------------------------------------- launch
extern "C" void kernel_launch(void* const* d_in, const int* in_sizes, int n_in,
                              void* d_out, int out_size, void* d_ws, size_t ws_size,
                              hipStream_t stream) {
  const float* q  = (const float*)d_in[0];
  const float* k  = (const float*)d_in[1];
  const float* v  = (const float*)d_in[2];
  const float* Wq = (const float*)d_in[3];
  const float* Wk = (const float*)d_in[4];
  const float* Wv = (const float*)d_in[5];
  const float* Wo = (const float*)d_in[6];
  float* out = (float*)d_out;

  char* ws = (char*)d_ws;
  size_t off = 0;
  float* cos_t = (float*)(ws + off); off += (size_t)T_ * 32 * 4;
  float* sin_t = (float*)(ws + off); off += (size_t)T_ * 32 * 4;
  ushort* Ab   = (ushort*)(ws + off); off += (size_t)4096 * 1024 * 2;
  ushort* Wqt  = (ushort*)(ws + off); off += (size_t)1024 * 1024 * 2;
  ushort* Wkvt = (ushort*)(ws + off); off += (size_t)512 * 1024 * 2;
  ushort* Wot  = (ushort*)(ws + off); off += (size_t)1024 * 1024 * 2;
  ushort* Kb   = (ushort*)(ws + off); off += (size_t)B_ * NKV_ * T_ * DK_ * 2;
  ushort* Vb   = (ushort*)(ws + off); off += (size_t)B_ * NKV_ * T_ * DK_ * 2;  // = Kb + KVOFF
  ushort* Qb   = (ushort*)(ws + off); off += (size_t)B_ * NH_ * T_ * DK_ * 2;
  ushort* Vt   = (ushort*)(ws + off); off += (size_t)B_ * NKV_ * T_ * DK_ * 2;

  dim3 blk(256);

  rope_table_kernel<<<dim3(256), blk, 0, stream>>>(cos_t, sin_t);

  wtrans_kernel<<<dim3(16, 16), blk, 0, stream>>>(Wq, Wqt, 1024);
  wtrans_kernel<<<dim3(4, 16), blk, 0, stream>>>(Wk, Wkvt, 256);
  wtrans_kernel<<<dim3(4, 16), blk, 0, stream>>>(Wv, Wkvt + (size_t)256 * 1024, 256);
  wtrans_kernel<<<dim3(16, 16), blk, 0, stream>>>(Wo, Wot, 1024);

  bgemm_kernel<<<dim3(8, 64), blk, 0, stream>>>((const void*)q, 1, nullptr, Wqt, (void*)Qb, 0, cos_t, sin_t);
  bgemm_kernel<<<dim3(4, 64), blk, 0, stream>>>((const void*)k, 1, (const void*)v, Wkvt, (void*)Kb, 4, cos_t, sin_t);

  vtrans_kernel<<<dim3(B_ * NKV_ * (T_ / 64)), blk, 0, stream>>>(Vb, Vt);

  attn_mfma_kernel<<<dim3(32, 16), blk, 0, stream>>>(Qb, Kb, Vt, Ab);

  bgemm_kernel<<<dim3(8, 64), blk, 0, stream>>>((const void*)Ab, 0, nullptr, Wot, (void*)out, 3, cos_t, sin_t);
}

// Round 5
// 121.187 us; speedup vs baseline: 8.1998x; 1.2230x over previous
//
#include <hip/hip_runtime.h>
#include <hip/hip_bf16.h>
#include <math.h>

#define B_ 2
#define T_ 2048
#define DM_ 1024
#define NH_ 16
#define NKV_ 4
#define G_ 4
#define DK_ 64
#define SCL 0.1803368784f   // 0.125 * log2(e) — folded into Q projection
#define KVOFF ((size_t)B_ * NKV_ * T_ * DK_)

typedef __attribute__((ext_vector_type(8))) short bf16x8;
typedef __attribute__((ext_vector_type(4))) float f32x4;
typedef __attribute__((ext_vector_type(8))) unsigned short u16x8;
typedef __attribute__((ext_vector_type(4))) unsigned short u16x4;

static __device__ __forceinline__ ushort f2bf(float x) {
  __hip_bfloat16 h = __float2bfloat16(x);
  return *reinterpret_cast<ushort*>(&h);
}

// ---------------------------------------------------------------- prep: RoPE tables + 4 weight transposes
// blocks [0,256): rope table; [256,512): Wq; [512,576): Wk; [576,640): Wv; [640,896): Wo
__global__ __launch_bounds__(256) void prep_kernel(const float* __restrict__ Wq,
                                                   const float* __restrict__ Wk,
                                                   const float* __restrict__ Wv,
                                                   const float* __restrict__ Wo,
                                                   ushort* __restrict__ WtAll,
                                                   ushort* __restrict__ Wot,
                                                   float* __restrict__ cos_t,
                                                   float* __restrict__ sin_t) {
  const int tid = threadIdx.x;
  int bid = blockIdx.x;
  if (bid < 256) {
    int idx = bid * 256 + tid;
    int t = idx >> 5, i = idx & 31;
    float invf = 1.0f / powf(10000.0f, (float)i / 32.0f);
    float ang = (float)t * invf;
    cos_t[idx] = cosf(ang);
    sin_t[idx] = sinf(ang);
    return;
  }
  bid -= 256;
  const float* W; ushort* Wt; int N, bx, by;
  if (bid < 256)      { W = Wq; Wt = WtAll;                       N = 1024; bx = bid & 15;        by = bid >> 4; }
  else if (bid < 320) { W = Wk; Wt = WtAll + (size_t)1024 * 1024; N = 256;  bx = (bid - 256) & 3; by = (bid - 256) >> 2; }
  else if (bid < 384) { W = Wv; Wt = WtAll + (size_t)1280 * 1024; N = 256;  bx = (bid - 320) & 3; by = (bid - 320) >> 2; }
  else                { W = Wo; Wt = Wot;                         N = 1024; bx = (bid - 384) & 15; by = (bid - 384) >> 4; }
  const int n0 = bx * 64, k0 = by * 64;
  __shared__ float tile[64 * 65];
#pragma unroll
  for (int it = 0; it < 4; ++it) {
    int lin = tid + it * 256;
    int r = lin >> 4, c4 = lin & 15;
    float4 v = *(const float4*)(W + (size_t)(k0 + r) * N + n0 + c4 * 4);
    tile[r * 65 + c4 * 4 + 0] = v.x;
    tile[r * 65 + c4 * 4 + 1] = v.y;
    tile[r * 65 + c4 * 4 + 2] = v.z;
    tile[r * 65 + c4 * 4 + 3] = v.w;
  }
  __syncthreads();
#pragma unroll
  for (int it = 0; it < 4; ++it) {
    int lin = tid + it * 256;
    int n = lin >> 4, c4 = lin & 15;
    u16x4 o;
#pragma unroll
    for (int j = 0; j < 4; ++j) o[j] = f2bf(tile[(c4 * 4 + j) * 65 + n]);
    *(u16x4*)(Wt + (size_t)(n0 + n) * 1024 + k0 + c4 * 4) = o;
  }
}

// ---------------------------------------------------------------- bf16 MFMA GEMM, 64x128 tile
// mode 5: merged QKV.  Bt=WtAll [1536][1024]; cols [0,1024)=Q(+RoPE*SCL)->Qb,
//         [1024,1280)=K(+RoPE)->Kb, [1280,1536)=V->Vt (transposed write).
//         A = q / k / v (f32), selected by n0.
// mode 3: O-projection.  A = Abf (bf16), Bt = Wot, out = Of (f32 [row][1024]).
__global__ __launch_bounds__(256, 2) void bgemm_kernel(const float* __restrict__ Aq,
                                                       const float* __restrict__ Ak,
                                                       const float* __restrict__ Av,
                                                       const ushort* __restrict__ Abf,
                                                       const ushort* __restrict__ Bt,
                                                       ushort* __restrict__ Qb,
                                                       ushort* __restrict__ Kb,
                                                       ushort* __restrict__ Vt,
                                                       float* __restrict__ Of, int mode,
                                                       const float* __restrict__ cos_t,
                                                       const float* __restrict__ sin_t) {
  const int tid = threadIdx.x;
  const int w = tid >> 6, lane = tid & 63;
  const int lr = lane & 15, lg = lane >> 4;
  const int wm = w >> 1, wn = w & 1;
  const int n0 = blockIdx.x * 128;
  const int m0 = blockIdx.y * 64;
  const bool f32A = (mode != 3);
  const float* Af = (n0 < 1024) ? Aq : (n0 < 1280 ? Ak : Av);

  __shared__ __align__(16) ushort As[64 * 64];    // pitch 128B, swizzled
  __shared__ __align__(16) ushort Bs[128 * 64];

  f32x4 acc[2][4];
#pragma unroll
  for (int mt = 0; mt < 2; ++mt)
#pragma unroll
    for (int nt = 0; nt < 4; ++nt) acc[mt][nt] = (f32x4){0.f, 0.f, 0.f, 0.f};

  const int sr = tid >> 3, sch = tid & 7;

  float4 apf[2][2];
  u16x8 apb[2];
  u16x8 bpf[4];
  if (f32A) {
#pragma unroll
    for (int it = 0; it < 2; ++it) {
      int r = sr + it * 32;
      apf[it][0] = *(const float4*)(Af + (size_t)(m0 + r) * 1024 + sch * 8);
      apf[it][1] = *(const float4*)(Af + (size_t)(m0 + r) * 1024 + sch * 8 + 4);
    }
  } else {
#pragma unroll
    for (int it = 0; it < 2; ++it) {
      int r = sr + it * 32;
      apb[it] = *(const u16x8*)(Abf + (size_t)(m0 + r) * 1024 + sch * 8);
    }
  }
#pragma unroll
  for (int it = 0; it < 4; ++it) {
    int r = sr + it * 32;
    bpf[it] = *(const u16x8*)(Bt + (size_t)(n0 + r) * 1024 + sch * 8);
  }

  for (int kt = 0; kt < 16; ++kt) {
    __syncthreads();
#pragma unroll
    for (int it = 0; it < 2; ++it) {
      int r = sr + it * 32;
      int byte = (r * 128 + sch * 16) ^ ((r & 7) << 4);
      u16x8 aw;
      if (f32A) {
        aw[0] = f2bf(apf[it][0].x); aw[1] = f2bf(apf[it][0].y);
        aw[2] = f2bf(apf[it][0].z); aw[3] = f2bf(apf[it][0].w);
        aw[4] = f2bf(apf[it][1].x); aw[5] = f2bf(apf[it][1].y);
        aw[6] = f2bf(apf[it][1].z); aw[7] = f2bf(apf[it][1].w);
      } else {
        aw = apb[it];
      }
      *(u16x8*)((char*)As + byte) = aw;
    }
#pragma unroll
    for (int it = 0; it < 4; ++it) {
      int r = sr + it * 32;
      int byte = (r * 128 + sch * 16) ^ ((r & 7) << 4);
      *(u16x8*)((char*)Bs + byte) = bpf[it];
    }
    __syncthreads();

    if (kt + 1 < 16) {
      if (f32A) {
#pragma unroll
        for (int it = 0; it < 2; ++it) {
          int r = sr + it * 32;
          apf[it][0] = *(const float4*)(Af + (size_t)(m0 + r) * 1024 + (kt + 1) * 64 + sch * 8);
          apf[it][1] = *(const float4*)(Af + (size_t)(m0 + r) * 1024 + (kt + 1) * 64 + sch * 8 + 4);
        }
      } else {
#pragma unroll
        for (int it = 0; it < 2; ++it) {
          int r = sr + it * 32;
          apb[it] = *(const u16x8*)(Abf + (size_t)(m0 + r) * 1024 + (kt + 1) * 64 + sch * 8);
        }
      }
#pragma unroll
      for (int it = 0; it < 4; ++it) {
        int r = sr + it * 32;
        bpf[it] = *(const u16x8*)(Bt + (size_t)(n0 + r) * 1024 + (kt + 1) * 64 + sch * 8);
      }
    }

    __builtin_amdgcn_s_setprio(1);
#pragma unroll
    for (int kc = 0; kc < 2; ++kc) {
      bf16x8 af[2], bfr[4];
#pragma unroll
      for (int mt = 0; mt < 2; ++mt) {
        int row = wm * 32 + mt * 16 + lr;
        int byte = (row * 128 + kc * 64 + lg * 16) ^ ((row & 7) << 4);
        af[mt] = *(bf16x8*)((char*)As + byte);
      }
#pragma unroll
      for (int nt = 0; nt < 4; ++nt) {
        int row = wn * 64 + nt * 16 + lr;
        int byte = (row * 128 + kc * 64 + lg * 16) ^ ((row & 7) << 4);
        bfr[nt] = *(bf16x8*)((char*)Bs + byte);
      }
#pragma unroll
      for (int mt = 0; mt < 2; ++mt)
#pragma unroll
        for (int nt = 0; nt < 4; ++nt)
          acc[mt][nt] = __builtin_amdgcn_mfma_f32_16x16x32_bf16(af[mt], bfr[nt], acc[mt][nt], 0, 0, 0);
    }
    __builtin_amdgcn_s_setprio(0);
  }

  // epilogue — C/D layout: col = lane&15, row = (lane>>4)*4 + r
  const int colbase = n0 + wn * 64;   // multiple of 64
  if (mode == 3) {
#pragma unroll
    for (int mt = 0; mt < 2; ++mt) {
      int rbase = m0 + wm * 32 + mt * 16 + lg * 4;
#pragma unroll
      for (int r = 0; r < 4; ++r)
#pragma unroll
        for (int nt = 0; nt < 4; ++nt)
          Of[(size_t)(rbase + r) * DM_ + colbase + nt * 16 + lr] = acc[mt][nt][r];
    }
  } else if (colbase >= 1280) {
    // V -> transposed write into Vt[(b*NKV+kvh)][d][t]
    int cb = colbase - 1280;
    int kvh = cb >> 6;
#pragma unroll
    for (int mt = 0; mt < 2; ++mt) {
      int row0 = m0 + wm * 32 + mt * 16 + lg * 4;
      int b = row0 >> 11, t0r = row0 & (T_ - 1);
#pragma unroll
      for (int nt = 0; nt < 4; ++nt) {
        int d = nt * 16 + lr;
        u16x4 o;
#pragma unroll
        for (int r = 0; r < 4; ++r) o[r] = f2bf(acc[mt][nt][r]);
        *(u16x4*)(Vt + ((size_t)(b * NKV_ + kvh) * DK_ + d) * T_ + t0r) = o;
      }
    }
  } else {
    // Q or K with RoPE
    const bool isQ = (colbase < 1024);
    const int cb = isQ ? colbase : (colbase - 1024);
    const int heads = isQ ? NH_ : NKV_;
    const float scl = isQ ? SCL : 1.0f;
    const int h = cb >> 6;
    ushort* O = isQ ? Qb : Kb;
#pragma unroll
    for (int mt = 0; mt < 2; ++mt) {
      int rbase = m0 + wm * 32 + mt * 16 + lg * 4;
#pragma unroll
      for (int r = 0; r < 4; ++r) {
        int row = rbase + r;
        int b = row >> 11, t = row & (T_ - 1);
#pragma unroll
        for (int nt = 0; nt < 2; ++nt) {          // partner is nt+2 (d+32), same lane
          int d = nt * 16 + lr;                   // < 32
          float c = cos_t[t * 32 + d], s = sin_t[t * 32 + d];
          float x1 = acc[mt][nt][r], x2 = acc[mt][nt + 2][r];
          size_t base = (((size_t)(b * heads + h)) * T_ + t) * DK_ + d;
          O[base] = f2bf((x1 * c - x2 * s) * scl);
          O[base + 32] = f2bf((x2 * c + x1 * s) * scl);
        }
      }
    }
  }
}

// ---------------------------------------------------------------- MFMA flash attention v3
// QBLK=64, grid (32, 32) = 1024 blocks (4/CU). 256 threads = 4 waves, wave owns 16 q-rows.
// Swapped QK^T (lane-local softmax), exp2 domain, MFMA-accumulated l (ones trick).
__global__ __launch_bounds__(256, 4) void attn_mfma_kernel(const ushort* __restrict__ Qb,
                                                           const ushort* __restrict__ Kb,
                                                           const ushort* __restrict__ Vt,
                                                           ushort* __restrict__ attn_out) {
  const int hb = blockIdx.x;
  const int b = hb >> 4;
  const int kv = (hb >> 2) & 3;
  const int g = hb & 3;
  const int h = kv * G_ + g;
  const int q0 = blockIdx.y * 64;

  const int tid = threadIdx.x;
  const int w = tid >> 6;
  const int lane = tid & 63;
  const int lr = lane & 15;
  const int lg = lane >> 4;

  __shared__ __align__(16) ushort Ks[64 * 64];
  __shared__ __align__(16) ushort Vs[64 * 64];   // [d][key]
  __shared__ __align__(16) ushort Ps[64 * 64];   // [q][key]

  const ushort* Qg = Qb + ((size_t)(b * NH_ + h) * T_ + q0) * DK_;
  const ushort* Kg = Kb + (size_t)(b * NKV_ + kv) * T_ * DK_;
  const ushort* Vg = Vt + (size_t)(b * NKV_ + kv) * DK_ * T_;

  // Q fragments straight from global (per-lane addresses, aligned 16B)
  bf16x8 aq[2];
#pragma unroll
  for (int kc = 0; kc < 2; ++kc)
    aq[kc] = *(const bf16x8*)(Qg + (size_t)(w * 16 + lr) * DK_ + kc * 32 + lg * 8);

  // all-ones B fragment for l = P @ 1
  bf16x8 vones;
#pragma unroll
  for (int j = 0; j < 8; ++j) vones[j] = (short)0x3F80;

  float m_run = -3.0e38f;          // row = lr (this lane's q-row for softmax)
  f32x4 oacc[4], lones;
#pragma unroll
  for (int dt = 0; dt < 4; ++dt) oacc[dt] = (f32x4){0.f, 0.f, 0.f, 0.f};
  lones = (f32x4){0.f, 0.f, 0.f, 0.f};

  const int sr = tid >> 3, sch = tid & 7;
  u16x8 kreg[2], vreg[2];
#pragma unroll
  for (int it = 0; it < 2; ++it) {
    int r = sr + it * 32;
    kreg[it] = *(const u16x8*)(Kg + (size_t)r * DK_ + sch * 8);
    vreg[it] = *(const u16x8*)(Vg + (size_t)r * T_ + sch * 8);
  }

  for (int kt = 0; kt < T_ / 64; ++kt) {
    __syncthreads();
#pragma unroll
    for (int it = 0; it < 2; ++it) {
      int r = sr + it * 32;
      int byte = (r * 128 + sch * 16) ^ ((r & 7) << 4);
      *(u16x8*)((char*)Ks + byte) = kreg[it];
      *(u16x8*)((char*)Vs + byte) = vreg[it];
    }
    __syncthreads();

    if (kt + 1 < T_ / 64) {
#pragma unroll
      for (int it = 0; it < 2; ++it) {
        int r = sr + it * 32;
        kreg[it] = *(const u16x8*)(Kg + (size_t)((kt + 1) * 64 + r) * DK_ + sch * 8);
        vreg[it] = *(const u16x8*)(Vg + (size_t)r * T_ + (kt + 1) * 64 + sch * 8);
      }
    }

    // ---- QK^T swapped: st[nt] = S^T, row = key = nt*16+lg*4+r, col = q = lr
    f32x4 st[4];
#pragma unroll
    for (int nt = 0; nt < 4; ++nt) st[nt] = (f32x4){0.f, 0.f, 0.f, 0.f};
    __builtin_amdgcn_s_setprio(1);
#pragma unroll
    for (int kc = 0; kc < 2; ++kc) {
      bf16x8 bk[4];
#pragma unroll
      for (int nt = 0; nt < 4; ++nt) {
        int krow = nt * 16 + lr;
        int byte = (krow * 128 + kc * 64 + lg * 16) ^ ((krow & 7) << 4);
        bk[nt] = *(bf16x8*)((char*)Ks + byte);
      }
#pragma unroll
      for (int nt = 0; nt < 4; ++nt)
        st[nt] = __builtin_amdgcn_mfma_f32_16x16x32_bf16(bk[nt], aq[kc], st[nt], 0, 0, 0);
    }
    __builtin_amdgcn_s_setprio(0);

    // ---- softmax: lane owns q-row lr, 16 of 64 keys; rest via 2 xor-shuffles
    float mx = fmaxf(fmaxf(st[0][0], st[0][1]), fmaxf(st[0][2], st[0][3]));
#pragma unroll
    for (int nt = 1; nt < 4; ++nt)
      mx = fmaxf(mx, fmaxf(fmaxf(st[nt][0], st[nt][1]), fmaxf(st[nt][2], st[nt][3])));
    mx = fmaxf(mx, __shfl_xor(mx, 16, 64));
    mx = fmaxf(mx, __shfl_xor(mx, 32, 64));

    if (__any(mx > m_run + 10.f)) {   // defer-max: rescale only on real growth
      float mnew = fmaxf(m_run, mx);
      float alpha = __builtin_amdgcn_exp2f(m_run - mnew);
      m_run = mnew;
#pragma unroll
      for (int r = 0; r < 4; ++r) {
        float a_r = __shfl(alpha, (lane & 48) | (lg * 4 + r), 64);
        lones[r] *= a_r;
#pragma unroll
        for (int dt = 0; dt < 4; ++dt) oacc[dt][r] *= a_r;
      }
    }

    // P = exp2(S - m), bf16 into LDS (swizzled); rowsum comes from MFMA
    {
      int prow = w * 16 + lr;
#pragma unroll
      for (int nt = 0; nt < 4; ++nt) {
        u16x4 pk;
#pragma unroll
        for (int r = 0; r < 4; ++r)
          pk[r] = f2bf(__builtin_amdgcn_exp2f(st[nt][r] - m_run));
        int byte = (prow * 128 + (nt * 16 + lg * 4) * 2) ^ ((prow & 7) << 4);
        *(u16x4*)((char*)Ps + byte) = pk;
      }
    }

    // ---- PV + l: oacc += P·V^T, lones += P·1
    __builtin_amdgcn_s_setprio(1);
#pragma unroll
    for (int kc = 0; kc < 2; ++kc) {
      int prow = w * 16 + lr;
      int pbyte = (prow * 128 + kc * 64 + lg * 16) ^ ((prow & 7) << 4);
      bf16x8 ap = *(bf16x8*)((char*)Ps + pbyte);
      lones = __builtin_amdgcn_mfma_f32_16x16x32_bf16(ap, vones, lones, 0, 0, 0);
#pragma unroll
      for (int dt = 0; dt < 4; ++dt) {
        int vrow = dt * 16 + lr;
        int byte = (vrow * 128 + kc * 64 + lg * 16) ^ ((vrow & 7) << 4);
        bf16x8 bv = *(bf16x8*)((char*)Vs + byte);
        oacc[dt] = __builtin_amdgcn_mfma_f32_16x16x32_bf16(ap, bv, oacc[dt], 0, 0, 0);
      }
    }
    __builtin_amdgcn_s_setprio(0);
  }

  // epilogue: l already in C-layout (lones[r] = rowsum for q-row lg*4+r)
#pragma unroll
  for (int r = 0; r < 4; ++r) {
    float inv = 1.0f / lones[r];
    int t = q0 + w * 16 + lg * 4 + r;
#pragma unroll
    for (int dt = 0; dt < 4; ++dt) {
      int d = dt * 16 + lr;
      attn_out[((size_t)b * T_ + t) * DM_ + h * DK_ + d] = f2bf(oacc[dt][r] * inv);
    }
  }
}

// ---------------------------------------------------------------- launch
extern "C" void kernel_launch(void* const* d_in, const int* in_sizes, int n_in,
                              void* d_out, int out_size, void* d_ws, size_t ws_size,
                              hipStream_t stream) {
  const float* q  = (const float*)d_in[0];
  const float* k  = (const float*)d_in[1];
  const float* v  = (const float*)d_in[2];
  const float* Wq = (const float*)d_in[3];
  const float* Wk = (const float*)d_in[4];
  const float* Wv = (const float*)d_in[5];
  const float* Wo = (const float*)d_in[6];
  float* out = (float*)d_out;

  char* ws = (char*)d_ws;
  size_t off = 0;
  float* cos_t  = (float*)(ws + off);  off += (size_t)T_ * 32 * 4;
  float* sin_t  = (float*)(ws + off);  off += (size_t)T_ * 32 * 4;
  ushort* Ab    = (ushort*)(ws + off); off += (size_t)4096 * 1024 * 2;   // attn out bf16
  ushort* WtAll = (ushort*)(ws + off); off += (size_t)1536 * 1024 * 2;   // [Q|K|V]^T
  ushort* Wot   = (ushort*)(ws + off); off += (size_t)1024 * 1024 * 2;
  ushort* Qb    = (ushort*)(ws + off); off += (size_t)B_ * NH_ * T_ * DK_ * 2;
  ushort* Kb    = (ushort*)(ws + off); off += (size_t)B_ * NKV_ * T_ * DK_ * 2;
  ushort* Vt    = (ushort*)(ws + off); off += (size_t)B_ * NKV_ * T_ * DK_ * 2;

  dim3 blk(256);

  prep_kernel<<<dim3(896), blk, 0, stream>>>(Wq, Wk, Wv, Wo, WtAll, Wot, cos_t, sin_t);

  // merged Q/K/V projection (N=1536)
  bgemm_kernel<<<dim3(12, 64), blk, 0, stream>>>(q, k, v, nullptr, WtAll,
                                                 Qb, Kb, Vt, nullptr, 5, cos_t, sin_t);

  attn_mfma_kernel<<<dim3(32, 32), blk, 0, stream>>>(Qb, Kb, Vt, Ab);

  // output projection -> d_out (f32)
  bgemm_kernel<<<dim3(8, 64), blk, 0, stream>>>(nullptr, nullptr, nullptr, Ab, Wot,
                                                nullptr, nullptr, nullptr, out, 3, cos_t, sin_t);
}

// Round 6
// 119.536 us; speedup vs baseline: 8.3131x; 1.0138x over previous
//
#include <hip/hip_runtime.h>
#include <hip/hip_bf16.h>
#include <math.h>

#define B_ 2
#define T_ 2048
#define DM_ 1024
#define NH_ 16
#define NKV_ 4
#define G_ 4
#define DK_ 64
#define SCL 0.1803368784f   // 0.125 * log2(e) — folded into Q projection
#define KVOFF ((size_t)B_ * NKV_ * T_ * DK_)

typedef __attribute__((ext_vector_type(8))) short bf16x8;
typedef __attribute__((ext_vector_type(4))) float f32x4;
typedef __attribute__((ext_vector_type(16))) float f32x16;
typedef __attribute__((ext_vector_type(8))) unsigned short u16x8;
typedef __attribute__((ext_vector_type(4))) unsigned short u16x4;

static __device__ __forceinline__ ushort f2bf(float x) {
  __hip_bfloat16 h = __float2bfloat16(x);
  return *reinterpret_cast<ushort*>(&h);
}

// ---------------------------------------------------------------- prep: RoPE tables + 4 weight transposes
__global__ __launch_bounds__(256) void prep_kernel(const float* __restrict__ Wq,
                                                   const float* __restrict__ Wk,
                                                   const float* __restrict__ Wv,
                                                   const float* __restrict__ Wo,
                                                   ushort* __restrict__ WtAll,
                                                   ushort* __restrict__ Wot,
                                                   float* __restrict__ cos_t,
                                                   float* __restrict__ sin_t) {
  const int tid = threadIdx.x;
  int bid = blockIdx.x;
  if (bid < 256) {
    int idx = bid * 256 + tid;
    int t = idx >> 5, i = idx & 31;
    float invf = 1.0f / powf(10000.0f, (float)i / 32.0f);
    float ang = (float)t * invf;
    cos_t[idx] = cosf(ang);
    sin_t[idx] = sinf(ang);
    return;
  }
  bid -= 256;
  const float* W; ushort* Wt; int N, bx, by;
  if (bid < 256)      { W = Wq; Wt = WtAll;                       N = 1024; bx = bid & 15;        by = bid >> 4; }
  else if (bid < 320) { W = Wk; Wt = WtAll + (size_t)1024 * 1024; N = 256;  bx = (bid - 256) & 3; by = (bid - 256) >> 2; }
  else if (bid < 384) { W = Wv; Wt = WtAll + (size_t)1280 * 1024; N = 256;  bx = (bid - 320) & 3; by = (bid - 320) >> 2; }
  else                { W = Wo; Wt = Wot;                         N = 1024; bx = (bid - 384) & 15; by = (bid - 384) >> 4; }
  const int n0 = bx * 64, k0 = by * 64;
  __shared__ float tile[64 * 65];
#pragma unroll
  for (int it = 0; it < 4; ++it) {
    int lin = tid + it * 256;
    int r = lin >> 4, c4 = lin & 15;
    float4 v = *(const float4*)(W + (size_t)(k0 + r) * N + n0 + c4 * 4);
    tile[r * 65 + c4 * 4 + 0] = v.x;
    tile[r * 65 + c4 * 4 + 1] = v.y;
    tile[r * 65 + c4 * 4 + 2] = v.z;
    tile[r * 65 + c4 * 4 + 3] = v.w;
  }
  __syncthreads();
#pragma unroll
  for (int it = 0; it < 4; ++it) {
    int lin = tid + it * 256;
    int n = lin >> 4, c4 = lin & 15;
    u16x4 o;
#pragma unroll
    for (int j = 0; j < 4; ++j) o[j] = f2bf(tile[(c4 * 4 + j) * 65 + n]);
    *(u16x4*)(Wt + (size_t)(n0 + n) * 1024 + k0 + c4 * 4) = o;
  }
}

// ---------------------------------------------------------------- bf16 MFMA GEMM, 64x128 tile (16x16x32)
__global__ __launch_bounds__(256, 2) void bgemm_kernel(const float* __restrict__ Aq,
                                                       const float* __restrict__ Ak,
                                                       const float* __restrict__ Av,
                                                       const ushort* __restrict__ Abf,
                                                       const ushort* __restrict__ Bt,
                                                       ushort* __restrict__ Qb,
                                                       ushort* __restrict__ Kb,
                                                       ushort* __restrict__ Vt,
                                                       float* __restrict__ Of, int mode,
                                                       const float* __restrict__ cos_t,
                                                       const float* __restrict__ sin_t) {
  const int tid = threadIdx.x;
  const int w = tid >> 6, lane = tid & 63;
  const int lr = lane & 15, lg = lane >> 4;
  const int wm = w >> 1, wn = w & 1;
  const int n0 = blockIdx.x * 128;
  const int m0 = blockIdx.y * 64;
  const bool f32A = (mode != 3);
  const float* Af = (n0 < 1024) ? Aq : (n0 < 1280 ? Ak : Av);

  __shared__ __align__(16) ushort As[64 * 64];
  __shared__ __align__(16) ushort Bs[128 * 64];

  f32x4 acc[2][4];
#pragma unroll
  for (int mt = 0; mt < 2; ++mt)
#pragma unroll
    for (int nt = 0; nt < 4; ++nt) acc[mt][nt] = (f32x4){0.f, 0.f, 0.f, 0.f};

  const int sr = tid >> 3, sch = tid & 7;

  float4 apf[2][2];
  u16x8 apb[2];
  u16x8 bpf[4];
  if (f32A) {
#pragma unroll
    for (int it = 0; it < 2; ++it) {
      int r = sr + it * 32;
      apf[it][0] = *(const float4*)(Af + (size_t)(m0 + r) * 1024 + sch * 8);
      apf[it][1] = *(const float4*)(Af + (size_t)(m0 + r) * 1024 + sch * 8 + 4);
    }
  } else {
#pragma unroll
    for (int it = 0; it < 2; ++it) {
      int r = sr + it * 32;
      apb[it] = *(const u16x8*)(Abf + (size_t)(m0 + r) * 1024 + sch * 8);
    }
  }
#pragma unroll
  for (int it = 0; it < 4; ++it) {
    int r = sr + it * 32;
    bpf[it] = *(const u16x8*)(Bt + (size_t)(n0 + r) * 1024 + sch * 8);
  }

  for (int kt = 0; kt < 16; ++kt) {
    __syncthreads();
#pragma unroll
    for (int it = 0; it < 2; ++it) {
      int r = sr + it * 32;
      int byte = (r * 128 + sch * 16) ^ ((r & 7) << 4);
      u16x8 aw;
      if (f32A) {
        aw[0] = f2bf(apf[it][0].x); aw[1] = f2bf(apf[it][0].y);
        aw[2] = f2bf(apf[it][0].z); aw[3] = f2bf(apf[it][0].w);
        aw[4] = f2bf(apf[it][1].x); aw[5] = f2bf(apf[it][1].y);
        aw[6] = f2bf(apf[it][1].z); aw[7] = f2bf(apf[it][1].w);
      } else {
        aw = apb[it];
      }
      *(u16x8*)((char*)As + byte) = aw;
    }
#pragma unroll
    for (int it = 0; it < 4; ++it) {
      int r = sr + it * 32;
      int byte = (r * 128 + sch * 16) ^ ((r & 7) << 4);
      *(u16x8*)((char*)Bs + byte) = bpf[it];
    }
    __syncthreads();

    if (kt + 1 < 16) {
      if (f32A) {
#pragma unroll
        for (int it = 0; it < 2; ++it) {
          int r = sr + it * 32;
          apf[it][0] = *(const float4*)(Af + (size_t)(m0 + r) * 1024 + (kt + 1) * 64 + sch * 8);
          apf[it][1] = *(const float4*)(Af + (size_t)(m0 + r) * 1024 + (kt + 1) * 64 + sch * 8 + 4);
        }
      } else {
#pragma unroll
        for (int it = 0; it < 2; ++it) {
          int r = sr + it * 32;
          apb[it] = *(const u16x8*)(Abf + (size_t)(m0 + r) * 1024 + (kt + 1) * 64 + sch * 8);
        }
      }
#pragma unroll
      for (int it = 0; it < 4; ++it) {
        int r = sr + it * 32;
        bpf[it] = *(const u16x8*)(Bt + (size_t)(n0 + r) * 1024 + (kt + 1) * 64 + sch * 8);
      }
    }

    __builtin_amdgcn_s_setprio(1);
#pragma unroll
    for (int kc = 0; kc < 2; ++kc) {
      bf16x8 af[2], bfr[4];
#pragma unroll
      for (int mt = 0; mt < 2; ++mt) {
        int row = wm * 32 + mt * 16 + lr;
        int byte = (row * 128 + kc * 64 + lg * 16) ^ ((row & 7) << 4);
        af[mt] = *(bf16x8*)((char*)As + byte);
      }
#pragma unroll
      for (int nt = 0; nt < 4; ++nt) {
        int row = wn * 64 + nt * 16 + lr;
        int byte = (row * 128 + kc * 64 + lg * 16) ^ ((row & 7) << 4);
        bfr[nt] = *(bf16x8*)((char*)Bs + byte);
      }
#pragma unroll
      for (int mt = 0; mt < 2; ++mt)
#pragma unroll
        for (int nt = 0; nt < 4; ++nt)
          acc[mt][nt] = __builtin_amdgcn_mfma_f32_16x16x32_bf16(af[mt], bfr[nt], acc[mt][nt], 0, 0, 0);
    }
    __builtin_amdgcn_s_setprio(0);
  }

  const int colbase = n0 + wn * 64;
  if (mode == 3) {
#pragma unroll
    for (int mt = 0; mt < 2; ++mt) {
      int rbase = m0 + wm * 32 + mt * 16 + lg * 4;
#pragma unroll
      for (int r = 0; r < 4; ++r)
#pragma unroll
        for (int nt = 0; nt < 4; ++nt)
          Of[(size_t)(rbase + r) * DM_ + colbase + nt * 16 + lr] = acc[mt][nt][r];
    }
  } else if (colbase >= 1280) {
    int cb = colbase - 1280;
    int kvh = cb >> 6;
#pragma unroll
    for (int mt = 0; mt < 2; ++mt) {
      int row0 = m0 + wm * 32 + mt * 16 + lg * 4;
      int b = row0 >> 11, t0r = row0 & (T_ - 1);
#pragma unroll
      for (int nt = 0; nt < 4; ++nt) {
        int d = nt * 16 + lr;
        u16x4 o;
#pragma unroll
        for (int r = 0; r < 4; ++r) o[r] = f2bf(acc[mt][nt][r]);
        *(u16x4*)(Vt + ((size_t)(b * NKV_ + kvh) * DK_ + d) * T_ + t0r) = o;
      }
    }
  } else {
    const bool isQ = (colbase < 1024);
    const int cb = isQ ? colbase : (colbase - 1024);
    const int heads = isQ ? NH_ : NKV_;
    const float scl = isQ ? SCL : 1.0f;
    const int h = cb >> 6;
    ushort* O = isQ ? Qb : Kb;
#pragma unroll
    for (int mt = 0; mt < 2; ++mt) {
      int rbase = m0 + wm * 32 + mt * 16 + lg * 4;
#pragma unroll
      for (int r = 0; r < 4; ++r) {
        int row = rbase + r;
        int b = row >> 11, t = row & (T_ - 1);
#pragma unroll
        for (int nt = 0; nt < 2; ++nt) {
          int d = nt * 16 + lr;
          float c = cos_t[t * 32 + d], s = sin_t[t * 32 + d];
          float x1 = acc[mt][nt][r], x2 = acc[mt][nt + 2][r];
          size_t base = (((size_t)(b * heads + h)) * T_ + t) * DK_ + d;
          O[base] = f2bf((x1 * c - x2 * s) * scl);
          O[base + 32] = f2bf((x2 * c + x1 * s) * scl);
        }
      }
    }
  }
}

// ---------------------------------------------------------------- MFMA flash attention v4 (32x32x16, in-reg P)
// grid (32 head-inst, 16 q-tiles). 4 waves x 32 q-rows = QBLK 128. KVBLK=64, dbuf LDS.
// Swapped QK^T: S^T = mfma(K, Q): col=q=lane&31, row=key=(reg&3)+8*(reg>>2)+4*(lane>>5).
__global__ __launch_bounds__(256, 2) void attn_mfma_kernel(const ushort* __restrict__ Qb,
                                                           const ushort* __restrict__ Kb,
                                                           const ushort* __restrict__ Vt,
                                                           ushort* __restrict__ attn_out) {
  const int hb = blockIdx.x;
  const int b = hb >> 4;
  const int kv = (hb >> 2) & 3;
  const int g = hb & 3;
  const int h = kv * G_ + g;
  const int q0 = blockIdx.y * 128;

  const int tid = threadIdx.x;
  const int w = tid >> 6;
  const int lane = tid & 63;
  const int l31 = lane & 31;
  const int hh = lane >> 5;

  __shared__ __align__(16) ushort Ks[2][64 * 64];   // [key][d], pitch 128B, swizzled
  __shared__ __align__(16) ushort Vs[2][64 * 64];   // [d][key], pitch 128B, swizzled

  const ushort* Qg = Qb + ((size_t)(b * NH_ + h) * T_ + q0 + w * 32) * DK_;
  const ushort* Kg = Kb + (size_t)(b * NKV_ + kv) * T_ * DK_;
  const ushort* Vg = Vt + (size_t)(b * NKV_ + kv) * DK_ * T_;

  // Q B-fragments: B[k=d][col=q] -> lane holds Q[q=l31][d = ks*16 + hh*8 + j]
  bf16x8 aq[4];
#pragma unroll
  for (int ks = 0; ks < 4; ++ks)
    aq[ks] = *(const bf16x8*)(Qg + (size_t)l31 * DK_ + ks * 16 + hh * 8);

  f32x16 oacc0{}, oacc1{};
  float m_run = -3.0e38f, l_run = 0.f;

  const int sr = tid >> 3, sch = tid & 7;
  const int swb = (sr & 7) << 4;
  u16x8 kreg[2], vreg[2];

#define LOADT(t)                                                                    \
  {                                                                                 \
    _Pragma("unroll") for (int it = 0; it < 2; ++it) {                              \
      int r = sr + it * 32;                                                         \
      kreg[it] = *(const u16x8*)(Kg + (size_t)((t) * 64 + r) * DK_ + sch * 8);      \
      vreg[it] = *(const u16x8*)(Vg + (size_t)r * T_ + (t) * 64 + sch * 8);         \
    }                                                                               \
  }
#define STAGEW(bufi)                                                                \
  {                                                                                 \
    _Pragma("unroll") for (int it = 0; it < 2; ++it) {                              \
      int r = sr + it * 32;                                                         \
      int byte = (r * 128 + sch * 16) ^ swb;                                        \
      *(u16x8*)((char*)Ks[bufi] + byte) = kreg[it];                                 \
      *(u16x8*)((char*)Vs[bufi] + byte) = vreg[it];                                 \
    }                                                                               \
  }

  LOADT(0);
  STAGEW(0);
  LOADT(1);
  __syncthreads();

  const int swf = (l31 & 7) << 4;   // fragment-read swizzle (row&7 == l31&7 for both row tiles)

  for (int kt = 0; kt < T_ / 64; ++kt) {
    const int cur = kt & 1;
    if (kt + 1 < T_ / 64) STAGEW(cur ^ 1);
    if (kt + 2 < T_ / 64) LOADT(kt + 2);

    // ---- QK^T: S^T[64key][32q], 2 key-tiles x 4 k-steps
    f32x16 st0{}, st1{};
    __builtin_amdgcn_s_setprio(1);
#pragma unroll
    for (int ks = 0; ks < 4; ++ks) {
      bf16x8 ak0 = *(bf16x8*)((char*)Ks[cur] + ((l31 * 128 + ks * 32 + hh * 16) ^ swf));
      bf16x8 ak1 = *(bf16x8*)((char*)Ks[cur] + (((32 + l31) * 128 + ks * 32 + hh * 16) ^ swf));
      st0 = __builtin_amdgcn_mfma_f32_32x32x16_bf16(ak0, aq[ks], st0, 0, 0, 0);
      st1 = __builtin_amdgcn_mfma_f32_32x32x16_bf16(ak1, aq[ks], st1, 0, 0, 0);
    }
    __builtin_amdgcn_s_setprio(0);

    // ---- softmax: lane owns q = l31; own 32 keys + partner(lane^32) 32 keys
    float mx = st0[0];
#pragma unroll
    for (int r = 1; r < 16; ++r) mx = fmaxf(mx, st0[r]);
#pragma unroll
    for (int r = 0; r < 16; ++r) mx = fmaxf(mx, st1[r]);
    mx = fmaxf(mx, __shfl_xor(mx, 32, 64));

    if (__any(mx > m_run + 10.f)) {   // defer-max
      float mnew = fmaxf(m_run, mx);
      float alpha = __builtin_amdgcn_exp2f(m_run - mnew);
      m_run = mnew;
      l_run *= alpha;
#pragma unroll
      for (int r = 0; r < 16; ++r) {
        int qr = (r & 3) + 8 * (r >> 2) + 4 * hh;
        float ar = __shfl(alpha, qr, 64);
        oacc0[r] *= ar;
        oacc1[r] *= ar;
      }
    }

    // P = exp2(S - m): pack pairs to bf16x2 u32; sum for l
    unsigned pk0[8], pk1[8];
    float ps = 0.f;
#pragma unroll
    for (int i = 0; i < 8; ++i) {
      float a0 = __builtin_amdgcn_exp2f(st0[2 * i] - m_run);
      float b0 = __builtin_amdgcn_exp2f(st0[2 * i + 1] - m_run);
      float a1 = __builtin_amdgcn_exp2f(st1[2 * i] - m_run);
      float b1 = __builtin_amdgcn_exp2f(st1[2 * i + 1] - m_run);
      ps += (a0 + b0) + (a1 + b1);
      asm("v_cvt_pk_bf16_f32 %0, %1, %2" : "=v"(pk0[i]) : "v"(a0), "v"(b0));
      asm("v_cvt_pk_bf16_f32 %0, %1, %2" : "=v"(pk1[i]) : "v"(a1), "v"(b1));
    }
    ps += __shfl_xor(ps, 32, 64);
    l_run += ps;

    // exchange halves: lane sends the pairs its partner needs
    unsigned rc0[4], rc1[4];
#pragma unroll
    for (int j = 0; j < 4; ++j) {
      const int ia = (j & 1) + ((j >> 1) << 2);   // {0,1,4,5}
      const int ib = ia + 2;                       // {2,3,6,7}
      rc0[j] = __shfl_xor(hh ? pk0[ia] : pk0[ib], 32, 64);
      rc1[j] = __shfl_xor(hh ? pk1[ia] : pk1[ib], 32, 64);
    }

    // ---- PV: O[32q][64d] += P·V, 4 k-steps x 2 d-tiles; P A-frags built in-register
    __builtin_amdgcn_s_setprio(1);
#pragma unroll
    for (int s = 0; s < 4; ++s) {
      const int sk = s & 1;
      unsigned wlo0, wlo1, whi0, whi1;
      if (s < 2) {
        wlo0 = hh ? rc0[2 * sk] : pk0[4 * sk];
        wlo1 = hh ? rc0[2 * sk + 1] : pk0[4 * sk + 1];
        whi0 = hh ? pk0[4 * sk + 2] : rc0[2 * sk];
        whi1 = hh ? pk0[4 * sk + 3] : rc0[2 * sk + 1];
      } else {
        wlo0 = hh ? rc1[2 * sk] : pk1[4 * sk];
        wlo1 = hh ? rc1[2 * sk + 1] : pk1[4 * sk + 1];
        whi0 = hh ? pk1[4 * sk + 2] : rc1[2 * sk];
        whi1 = hh ? pk1[4 * sk + 3] : rc1[2 * sk + 1];
      }
      int4 fr = {(int)wlo0, (int)wlo1, (int)whi0, (int)whi1};
      bf16x8 ap = *(bf16x8*)&fr;
      bf16x8 bv0 = *(bf16x8*)((char*)Vs[cur] + ((l31 * 128 + s * 32 + hh * 16) ^ swf));
      bf16x8 bv1 = *(bf16x8*)((char*)Vs[cur] + (((32 + l31) * 128 + s * 32 + hh * 16) ^ swf));
      oacc0 = __builtin_amdgcn_mfma_f32_32x32x16_bf16(ap, bv0, oacc0, 0, 0, 0);
      oacc1 = __builtin_amdgcn_mfma_f32_32x32x16_bf16(ap, bv1, oacc1, 0, 0, 0);
    }
    __builtin_amdgcn_s_setprio(0);

    __syncthreads();
  }

  // epilogue: row q = (r&3)+8*(r>>2)+4*hh (+ wave base), col d = dtile*32 + l31
  float inv = 1.0f / l_run;
#pragma unroll
  for (int r = 0; r < 16; ++r) {
    int qr = (r & 3) + 8 * (r >> 2) + 4 * hh;
    float ir = __shfl(inv, qr, 64);
    int t = q0 + w * 32 + qr;
    size_t base = ((size_t)b * T_ + t) * DM_ + h * DK_;
    attn_out[base + l31] = f2bf(oacc0[r] * ir);
    attn_out[base + 32 + l31] = f2bf(oacc1[r] * ir);
  }
#undef LOADT
#undef STAGEW
}

// ---------------------------------------------------------------- launch
extern "C" void kernel_launch(void* const* d_in, const int* in_sizes, int n_in,
                              void* d_out, int out_size, void* d_ws, size_t ws_size,
                              hipStream_t stream) {
  const float* q  = (const float*)d_in[0];
  const float* k  = (const float*)d_in[1];
  const float* v  = (const float*)d_in[2];
  const float* Wq = (const float*)d_in[3];
  const float* Wk = (const float*)d_in[4];
  const float* Wv = (const float*)d_in[5];
  const float* Wo = (const float*)d_in[6];
  float* out = (float*)d_out;

  char* ws = (char*)d_ws;
  size_t off = 0;
  float* cos_t  = (float*)(ws + off);  off += (size_t)T_ * 32 * 4;
  float* sin_t  = (float*)(ws + off);  off += (size_t)T_ * 32 * 4;
  ushort* Ab    = (ushort*)(ws + off); off += (size_t)4096 * 1024 * 2;   // attn out bf16
  ushort* WtAll = (ushort*)(ws + off); off += (size_t)1536 * 1024 * 2;   // [Q|K|V]^T
  ushort* Wot   = (ushort*)(ws + off); off += (size_t)1024 * 1024 * 2;
  ushort* Qb    = (ushort*)(ws + off); off += (size_t)B_ * NH_ * T_ * DK_ * 2;
  ushort* Kb    = (ushort*)(ws + off); off += (size_t)B_ * NKV_ * T_ * DK_ * 2;
  ushort* Vt    = (ushort*)(ws + off); off += (size_t)B_ * NKV_ * T_ * DK_ * 2;

  dim3 blk(256);

  prep_kernel<<<dim3(896), blk, 0, stream>>>(Wq, Wk, Wv, Wo, WtAll, Wot, cos_t, sin_t);

  // merged Q/K/V projection (N=1536)
  bgemm_kernel<<<dim3(12, 64), blk, 0, stream>>>(q, k, v, nullptr, WtAll,
                                                 Qb, Kb, Vt, nullptr, 5, cos_t, sin_t);

  attn_mfma_kernel<<<dim3(32, 16), blk, 0, stream>>>(Qb, Kb, Vt, Ab);

  // output projection -> d_out (f32)
  bgemm_kernel<<<dim3(8, 64), blk, 0, stream>>>(nullptr, nullptr, nullptr, Ab, Wot,
                                                nullptr, nullptr, nullptr, out, 3, cos_t, sin_t);
}

// Round 7
// 115.739 us; speedup vs baseline: 8.5858x; 1.0328x over previous
//
#include <hip/hip_runtime.h>
#include <hip/hip_bf16.h>
#include <math.h>

#define B_ 2
#define T_ 2048
#define DM_ 1024
#define NH_ 16
#define NKV_ 4
#define G_ 4
#define DK_ 64
#define SCL 0.1803368784f   // 0.125 * log2(e) — folded into Q projection

typedef __attribute__((ext_vector_type(8))) short bf16x8;
typedef __attribute__((ext_vector_type(4))) float f32x4;
typedef __attribute__((ext_vector_type(16))) float f32x16;
typedef __attribute__((ext_vector_type(8))) unsigned short u16x8;
typedef __attribute__((ext_vector_type(4))) unsigned short u16x4;

static __device__ __forceinline__ ushort f2bf(float x) {
  __hip_bfloat16 h = __float2bfloat16(x);
  return *reinterpret_cast<ushort*>(&h);
}

// ---------------------------------------------------------------- prep: RoPE tables + 4 weight transposes
__global__ __launch_bounds__(256) void prep_kernel(const float* __restrict__ Wq,
                                                   const float* __restrict__ Wk,
                                                   const float* __restrict__ Wv,
                                                   const float* __restrict__ Wo,
                                                   ushort* __restrict__ WtAll,
                                                   ushort* __restrict__ Wot,
                                                   float* __restrict__ cos_t,
                                                   float* __restrict__ sin_t) {
  const int tid = threadIdx.x;
  int bid = blockIdx.x;
  if (bid < 256) {
    int idx = bid * 256 + tid;
    int t = idx >> 5, i = idx & 31;
    float invf = 1.0f / powf(10000.0f, (float)i / 32.0f);
    float ang = (float)t * invf;
    cos_t[idx] = cosf(ang);
    sin_t[idx] = sinf(ang);
    return;
  }
  bid -= 256;
  const float* W; ushort* Wt; int N, bx, by;
  if (bid < 256)      { W = Wq; Wt = WtAll;                       N = 1024; bx = bid & 15;        by = bid >> 4; }
  else if (bid < 320) { W = Wk; Wt = WtAll + (size_t)1024 * 1024; N = 256;  bx = (bid - 256) & 3; by = (bid - 256) >> 2; }
  else if (bid < 384) { W = Wv; Wt = WtAll + (size_t)1280 * 1024; N = 256;  bx = (bid - 320) & 3; by = (bid - 320) >> 2; }
  else                { W = Wo; Wt = Wot;                         N = 1024; bx = (bid - 384) & 15; by = (bid - 384) >> 4; }
  const int n0 = bx * 64, k0 = by * 64;
  __shared__ float tile[64 * 65];
#pragma unroll
  for (int it = 0; it < 4; ++it) {
    int lin = tid + it * 256;
    int r = lin >> 4, c4 = lin & 15;
    float4 v = *(const float4*)(W + (size_t)(k0 + r) * N + n0 + c4 * 4);
    tile[r * 65 + c4 * 4 + 0] = v.x;
    tile[r * 65 + c4 * 4 + 1] = v.y;
    tile[r * 65 + c4 * 4 + 2] = v.z;
    tile[r * 65 + c4 * 4 + 3] = v.w;
  }
  __syncthreads();
#pragma unroll
  for (int it = 0; it < 4; ++it) {
    int lin = tid + it * 256;
    int n = lin >> 4, c4 = lin & 15;
    u16x4 o;
#pragma unroll
    for (int j = 0; j < 4; ++j) o[j] = f2bf(tile[(c4 * 4 + j) * 65 + n]);
    *(u16x4*)(Wt + (size_t)(n0 + n) * 1024 + k0 + c4 * 4) = o;
  }
}

// ---------------------------------------------------------------- bf16 MFMA GEMM, 64x128 tile (16x16x32)
__global__ __launch_bounds__(256, 2) void bgemm_kernel(const float* __restrict__ Aq,
                                                       const float* __restrict__ Ak,
                                                       const float* __restrict__ Av,
                                                       const ushort* __restrict__ Abf,
                                                       const ushort* __restrict__ Bt,
                                                       ushort* __restrict__ Qb,
                                                       ushort* __restrict__ Kb,
                                                       ushort* __restrict__ Vt,
                                                       float* __restrict__ Of, int mode,
                                                       const float* __restrict__ cos_t,
                                                       const float* __restrict__ sin_t) {
  const int tid = threadIdx.x;
  const int w = tid >> 6, lane = tid & 63;
  const int lr = lane & 15, lg = lane >> 4;
  const int wm = w >> 1, wn = w & 1;
  const int n0 = blockIdx.x * 128;
  const int m0 = blockIdx.y * 64;
  const bool f32A = (mode != 3);
  const float* Af = (n0 < 1024) ? Aq : (n0 < 1280 ? Ak : Av);

  __shared__ __align__(16) ushort As[64 * 64];
  __shared__ __align__(16) ushort Bs[128 * 64];

  f32x4 acc[2][4];
#pragma unroll
  for (int mt = 0; mt < 2; ++mt)
#pragma unroll
    for (int nt = 0; nt < 4; ++nt) acc[mt][nt] = (f32x4){0.f, 0.f, 0.f, 0.f};

  const int sr = tid >> 3, sch = tid & 7;

  float4 apf[2][2];
  u16x8 apb[2];
  u16x8 bpf[4];
  if (f32A) {
#pragma unroll
    for (int it = 0; it < 2; ++it) {
      int r = sr + it * 32;
      apf[it][0] = *(const float4*)(Af + (size_t)(m0 + r) * 1024 + sch * 8);
      apf[it][1] = *(const float4*)(Af + (size_t)(m0 + r) * 1024 + sch * 8 + 4);
    }
  } else {
#pragma unroll
    for (int it = 0; it < 2; ++it) {
      int r = sr + it * 32;
      apb[it] = *(const u16x8*)(Abf + (size_t)(m0 + r) * 1024 + sch * 8);
    }
  }
#pragma unroll
  for (int it = 0; it < 4; ++it) {
    int r = sr + it * 32;
    bpf[it] = *(const u16x8*)(Bt + (size_t)(n0 + r) * 1024 + sch * 8);
  }

  for (int kt = 0; kt < 16; ++kt) {
    __syncthreads();
#pragma unroll
    for (int it = 0; it < 2; ++it) {
      int r = sr + it * 32;
      int byte = (r * 128 + sch * 16) ^ ((r & 7) << 4);
      u16x8 aw;
      if (f32A) {
        aw[0] = f2bf(apf[it][0].x); aw[1] = f2bf(apf[it][0].y);
        aw[2] = f2bf(apf[it][0].z); aw[3] = f2bf(apf[it][0].w);
        aw[4] = f2bf(apf[it][1].x); aw[5] = f2bf(apf[it][1].y);
        aw[6] = f2bf(apf[it][1].z); aw[7] = f2bf(apf[it][1].w);
      } else {
        aw = apb[it];
      }
      *(u16x8*)((char*)As + byte) = aw;
    }
#pragma unroll
    for (int it = 0; it < 4; ++it) {
      int r = sr + it * 32;
      int byte = (r * 128 + sch * 16) ^ ((r & 7) << 4);
      *(u16x8*)((char*)Bs + byte) = bpf[it];
    }
    __syncthreads();

    if (kt + 1 < 16) {
      if (f32A) {
#pragma unroll
        for (int it = 0; it < 2; ++it) {
          int r = sr + it * 32;
          apf[it][0] = *(const float4*)(Af + (size_t)(m0 + r) * 1024 + (kt + 1) * 64 + sch * 8);
          apf[it][1] = *(const float4*)(Af + (size_t)(m0 + r) * 1024 + (kt + 1) * 64 + sch * 8 + 4);
        }
      } else {
#pragma unroll
        for (int it = 0; it < 2; ++it) {
          int r = sr + it * 32;
          apb[it] = *(const u16x8*)(Abf + (size_t)(m0 + r) * 1024 + (kt + 1) * 64 + sch * 8);
        }
      }
#pragma unroll
      for (int it = 0; it < 4; ++it) {
        int r = sr + it * 32;
        bpf[it] = *(const u16x8*)(Bt + (size_t)(n0 + r) * 1024 + (kt + 1) * 64 + sch * 8);
      }
    }

    __builtin_amdgcn_s_setprio(1);
#pragma unroll
    for (int kc = 0; kc < 2; ++kc) {
      bf16x8 af[2], bfr[4];
#pragma unroll
      for (int mt = 0; mt < 2; ++mt) {
        int row = wm * 32 + mt * 16 + lr;
        int byte = (row * 128 + kc * 64 + lg * 16) ^ ((row & 7) << 4);
        af[mt] = *(bf16x8*)((char*)As + byte);
      }
#pragma unroll
      for (int nt = 0; nt < 4; ++nt) {
        int row = wn * 64 + nt * 16 + lr;
        int byte = (row * 128 + kc * 64 + lg * 16) ^ ((row & 7) << 4);
        bfr[nt] = *(bf16x8*)((char*)Bs + byte);
      }
#pragma unroll
      for (int mt = 0; mt < 2; ++mt)
#pragma unroll
        for (int nt = 0; nt < 4; ++nt)
          acc[mt][nt] = __builtin_amdgcn_mfma_f32_16x16x32_bf16(af[mt], bfr[nt], acc[mt][nt], 0, 0, 0);
    }
    __builtin_amdgcn_s_setprio(0);
  }

  const int colbase = n0 + wn * 64;
  if (mode == 3) {
#pragma unroll
    for (int mt = 0; mt < 2; ++mt) {
      int rbase = m0 + wm * 32 + mt * 16 + lg * 4;
#pragma unroll
      for (int r = 0; r < 4; ++r)
#pragma unroll
        for (int nt = 0; nt < 4; ++nt)
          Of[(size_t)(rbase + r) * DM_ + colbase + nt * 16 + lr] = acc[mt][nt][r];
    }
  } else if (colbase >= 1280) {
    int cb = colbase - 1280;
    int kvh = cb >> 6;
#pragma unroll
    for (int mt = 0; mt < 2; ++mt) {
      int row0 = m0 + wm * 32 + mt * 16 + lg * 4;
      int b = row0 >> 11, t0r = row0 & (T_ - 1);
#pragma unroll
      for (int nt = 0; nt < 4; ++nt) {
        int d = nt * 16 + lr;
        u16x4 o;
#pragma unroll
        for (int r = 0; r < 4; ++r) o[r] = f2bf(acc[mt][nt][r]);
        *(u16x4*)(Vt + ((size_t)(b * NKV_ + kvh) * DK_ + d) * T_ + t0r) = o;
      }
    }
  } else {
    const bool isQ = (colbase < 1024);
    const int cb = isQ ? colbase : (colbase - 1024);
    const int heads = isQ ? NH_ : NKV_;
    const float scl = isQ ? SCL : 1.0f;
    const int h = cb >> 6;
    ushort* O = isQ ? Qb : Kb;
#pragma unroll
    for (int mt = 0; mt < 2; ++mt) {
      int rbase = m0 + wm * 32 + mt * 16 + lg * 4;
#pragma unroll
      for (int r = 0; r < 4; ++r) {
        int row = rbase + r;
        int b = row >> 11, t = row & (T_ - 1);
#pragma unroll
        for (int nt = 0; nt < 2; ++nt) {
          int d = nt * 16 + lr;
          float c = cos_t[t * 32 + d], s = sin_t[t * 32 + d];
          float x1 = acc[mt][nt][r], x2 = acc[mt][nt + 2][r];
          size_t base = (((size_t)(b * heads + h)) * T_ + t) * DK_ + d;
          O[base] = f2bf((x1 * c - x2 * s) * scl);
          O[base + 32] = f2bf((x2 * c + x1 * s) * scl);
        }
      }
    }
  }
}

// ---------------------------------------------------------------- MFMA flash attention v5
// 32x32x16 core, 2-wave blocks (128 thr), QBLK=64 (32 q/wave), grid (32, 32) = 1024 blocks.
// Swapped QK^T: S^T[key][q]; V staged with key bits 2<->3 swapped so PV A-frags are
// consecutive C-register pairs of the lane's own st regs (zero cross-lane exchange).
__global__ __launch_bounds__(128, 2) void attn_mfma_kernel(const ushort* __restrict__ Qb,
                                                           const ushort* __restrict__ Kb,
                                                           const ushort* __restrict__ Vt,
                                                           ushort* __restrict__ attn_out) {
  const int hb = blockIdx.x;
  const int b = hb >> 4;
  const int kv = (hb >> 2) & 3;
  const int g = hb & 3;
  const int h = kv * G_ + g;
  const int q0 = blockIdx.y * 64;

  const int tid = threadIdx.x;
  const int w = tid >> 6;          // 0..1
  const int lane = tid & 63;
  const int l31 = lane & 31;
  const int hh = lane >> 5;

  __shared__ __align__(16) ushort Ks[2][64 * 64];   // [key][d], pitch 128B, row-XOR swizzle
  __shared__ __align__(16) ushort Vs[2][64 * 64];   // [d][key-permuted], pitch 128B, swizzled

  const ushort* Qg = Qb + ((size_t)(b * NH_ + h) * T_ + q0 + w * 32) * DK_;
  const ushort* Kg = Kb + (size_t)(b * NKV_ + kv) * T_ * DK_;
  const ushort* Vg = Vt + (size_t)(b * NKV_ + kv) * DK_ * T_;

  // Q B-fragments from global: lane holds Q[q=l31][d = ks*16 + hh*8 + j]
  bf16x8 aq[4];
#pragma unroll
  for (int ks = 0; ks < 4; ++ks)
    aq[ks] = *(const bf16x8*)(Qg + (size_t)l31 * DK_ + ks * 16 + hh * 8);

  f32x16 oacc0{}, oacc1{};
  float m_run = -3.0e38f, l_run = 0.f;

  const int sr = tid >> 3, sch = tid & 7;   // 16 row-groups x 8 chunks
  const int vcol0b = 8 * (sch & 1) + 32 * (sch >> 1);   // byte of first permuted V column group
  u16x8 kreg[4], vreg[4];

#define LOADT(t)                                                                    \
  {                                                                                 \
    _Pragma("unroll") for (int it = 0; it < 4; ++it) {                              \
      int r = sr + it * 16;                                                         \
      kreg[it] = *(const u16x8*)(Kg + (size_t)((t) * 64 + r) * DK_ + sch * 8);      \
      vreg[it] = *(const u16x8*)(Vg + (size_t)r * T_ + (t) * 64 + sch * 8);         \
    }                                                                               \
  }
#define STAGEW(bufi)                                                                \
  {                                                                                 \
    _Pragma("unroll") for (int it = 0; it < 4; ++it) {                              \
      int r = sr + it * 16;                                                         \
      int swz = (r & 7) << 4;                                                       \
      *(u16x8*)((char*)Ks[bufi] + ((r * 128 + sch * 16) ^ swz)) = kreg[it];         \
      int vx = (r * 128 + vcol0b) ^ swz;                                            \
      u16x4 lo, hi;                                                                 \
      _Pragma("unroll") for (int j = 0; j < 4; ++j) { lo[j] = vreg[it][j]; hi[j] = vreg[it][4 + j]; } \
      *(u16x4*)((char*)Vs[bufi] + vx) = lo;                                         \
      *(u16x4*)((char*)Vs[bufi] + (vx ^ 16)) = hi;                                  \
    }                                                                               \
  }

  LOADT(0);
  STAGEW(0);
  LOADT(1);
  __syncthreads();

  const int swf = (l31 & 7) << 4;   // fragment-read swizzle (rows l31 and 32+l31 share row&7)

  for (int kt = 0; kt < T_ / 64; ++kt) {
    const int cur = kt & 1;
    if (kt + 1 < T_ / 64) STAGEW(cur ^ 1);
    if (kt + 2 < T_ / 64) LOADT(kt + 2);

    // ---- QK^T: S^T[64key][32q] = K · Q^T
    f32x16 st0{}, st1{};
    __builtin_amdgcn_s_setprio(1);
#pragma unroll
    for (int ks = 0; ks < 4; ++ks) {
      bf16x8 ak0 = *(bf16x8*)((char*)Ks[cur] + ((l31 * 128 + ks * 32 + hh * 16) ^ swf));
      bf16x8 ak1 = *(bf16x8*)((char*)Ks[cur] + (((32 + l31) * 128 + ks * 32 + hh * 16) ^ swf));
      st0 = __builtin_amdgcn_mfma_f32_32x32x16_bf16(ak0, aq[ks], st0, 0, 0, 0);
      st1 = __builtin_amdgcn_mfma_f32_32x32x16_bf16(ak1, aq[ks], st1, 0, 0, 0);
    }
    __builtin_amdgcn_s_setprio(0);

    // ---- softmax: lane owns q = l31 (cols); keys split across hh halves
    float mx = st0[0];
#pragma unroll
    for (int r = 1; r < 16; ++r) mx = fmaxf(mx, st0[r]);
#pragma unroll
    for (int r = 0; r < 16; ++r) mx = fmaxf(mx, st1[r]);
    mx = fmaxf(mx, __shfl_xor(mx, 32, 64));

    if (__any(mx > m_run + 10.f)) {   // defer-max
      float mnew = fmaxf(m_run, mx);
      float alpha = __builtin_amdgcn_exp2f(m_run - mnew);
      m_run = mnew;
      l_run *= alpha;
#pragma unroll
      for (int r = 0; r < 16; ++r) {
        int qr = (r & 3) + 8 * (r >> 2) + 4 * hh;
        float ar = __shfl(alpha, qr, 64);
        oacc0[r] *= ar;
        oacc1[r] *= ar;
      }
    }

    // P = exp2(S - m) in place; accumulate own-half rowsum (cross-half deferred)
    float ps = 0.f;
#pragma unroll
    for (int r = 0; r < 16; ++r) {
      st0[r] = __builtin_amdgcn_exp2f(st0[r] - m_run);
      st1[r] = __builtin_amdgcn_exp2f(st1[r] - m_run);
      ps += st0[r] + st1[r];
    }
    l_run += ps;

    // ---- PV: A-frag for step s = regs [base..base+7] of st0 (s<2) / st1 (s>=2)
    __builtin_amdgcn_s_setprio(1);
#pragma unroll
    for (int s = 0; s < 4; ++s) {
      const int base = (s & 1) * 8;
      u16x8 pw;
#pragma unroll
      for (int j = 0; j < 8; ++j)
        pw[j] = f2bf((s < 2) ? st0[base + j] : st1[base + j]);
      bf16x8 pa = *(bf16x8*)&pw;
      bf16x8 bv0 = *(bf16x8*)((char*)Vs[cur] + ((l31 * 128 + s * 32 + hh * 16) ^ swf));
      bf16x8 bv1 = *(bf16x8*)((char*)Vs[cur] + (((32 + l31) * 128 + s * 32 + hh * 16) ^ swf));
      oacc0 = __builtin_amdgcn_mfma_f32_32x32x16_bf16(pa, bv0, oacc0, 0, 0, 0);
      oacc1 = __builtin_amdgcn_mfma_f32_32x32x16_bf16(pa, bv1, oacc1, 0, 0, 0);
    }
    __builtin_amdgcn_s_setprio(0);

    __syncthreads();
  }

  // epilogue: l = own half + partner half; row q = (r&3)+8*(r>>2)+4*hh, col d = dtile*32 + l31
  float l_tot = l_run + __shfl_xor(l_run, 32, 64);
  float inv = 1.0f / l_tot;
#pragma unroll
  for (int r = 0; r < 16; ++r) {
    int qr = (r & 3) + 8 * (r >> 2) + 4 * hh;
    float ir = __shfl(inv, qr, 64);
    int t = q0 + w * 32 + qr;
    size_t base = ((size_t)b * T_ + t) * DM_ + h * DK_;
    attn_out[base + l31] = f2bf(oacc0[r] * ir);
    attn_out[base + 32 + l31] = f2bf(oacc1[r] * ir);
  }
#undef LOADT
#undef STAGEW
}

// ---------------------------------------------------------------- launch
extern "C" void kernel_launch(void* const* d_in, const int* in_sizes, int n_in,
                              void* d_out, int out_size, void* d_ws, size_t ws_size,
                              hipStream_t stream) {
  const float* q  = (const float*)d_in[0];
  const float* k  = (const float*)d_in[1];
  const float* v  = (const float*)d_in[2];
  const float* Wq = (const float*)d_in[3];
  const float* Wk = (const float*)d_in[4];
  const float* Wv = (const float*)d_in[5];
  const float* Wo = (const float*)d_in[6];
  float* out = (float*)d_out;

  char* ws = (char*)d_ws;
  size_t off = 0;
  float* cos_t  = (float*)(ws + off);  off += (size_t)T_ * 32 * 4;
  float* sin_t  = (float*)(ws + off);  off += (size_t)T_ * 32 * 4;
  ushort* Ab    = (ushort*)(ws + off); off += (size_t)4096 * 1024 * 2;   // attn out bf16
  ushort* WtAll = (ushort*)(ws + off); off += (size_t)1536 * 1024 * 2;   // [Q|K|V]^T
  ushort* Wot   = (ushort*)(ws + off); off += (size_t)1024 * 1024 * 2;
  ushort* Qb    = (ushort*)(ws + off); off += (size_t)B_ * NH_ * T_ * DK_ * 2;
  ushort* Kb    = (ushort*)(ws + off); off += (size_t)B_ * NKV_ * T_ * DK_ * 2;
  ushort* Vt    = (ushort*)(ws + off); off += (size_t)B_ * NKV_ * T_ * DK_ * 2;

  prep_kernel<<<dim3(896), dim3(256), 0, stream>>>(Wq, Wk, Wv, Wo, WtAll, Wot, cos_t, sin_t);

  // merged Q/K/V projection (N=1536)
  bgemm_kernel<<<dim3(12, 64), dim3(256), 0, stream>>>(q, k, v, nullptr, WtAll,
                                                       Qb, Kb, Vt, nullptr, 5, cos_t, sin_t);

  attn_mfma_kernel<<<dim3(32, 32), dim3(128), 0, stream>>>(Qb, Kb, Vt, Ab);

  // output projection -> d_out (f32)
  bgemm_kernel<<<dim3(8, 64), dim3(256), 0, stream>>>(nullptr, nullptr, nullptr, Ab, Wot,
                                                      nullptr, nullptr, nullptr, out, 3, cos_t, sin_t);
}